// Round 2
// baseline (6285.463 us; speedup 1.0000x reference)
//
#include <hip/hip_runtime.h>
#include <math.h>

namespace {
constexpr int N_ = 50000;
constexpr int E_ = 400000;
constexpr int F_ = 32;
constexpr int K_ = 16;
constexpr int B_ = 10;
constexpr float CUT_ = 10.0f;
constexpr float EPS_ = 1e-8f;
constexpr size_t WS_FLOATS = 106800000;  // exact sum of all regions below
}

// Static device scratch: do NOT rely on d_ws (size unknown -> round-1 abort was
// an aperture violation from writing past it). 427 MB BSS, allocated at module load.
__device__ float g_ws[WS_FLOATS];

__constant__ float c_binom[K_] = {1.f,15.f,105.f,455.f,1365.f,3003.f,5005.f,6435.f,
                                  6435.f,5005.f,3003.f,1365.f,455.f,105.f,15.f,1.f};

__device__ __forceinline__ float sigm(float x) { return 1.f / (1.f + expf(-x)); }

// ---------------- utility fills ----------------
__global__ void fill_kernel(float* __restrict__ p, size_t n, float v) {
  size_t i = (size_t)blockIdx.x * blockDim.x + threadIdx.x;
  size_t st = (size_t)gridDim.x * blockDim.x;
  for (; i < n; i += st) p[i] = v;
}

__global__ void init_embed_kernel(float* __restrict__ s, const float* __restrict__ embed,
                                  const int* __restrict__ Z) {
  int gid = blockIdx.x * blockDim.x + threadIdx.x;  // over N*F
  int n = gid >> 5, f = gid & 31;
  s[gid] = embed[Z[n] * F_ + f];
}

__global__ void init_gs_kernel(float* __restrict__ Gs, const float* __restrict__ w_out) {
  int gid = blockIdx.x * blockDim.x + threadIdx.x;  // over N*F
  Gs[gid] = -w_out[gid & 31];
}

// ---------------- geometry / basis ----------------
__global__ void geom_kernel(const float* __restrict__ pos, const int* __restrict__ dst,
                            const int* __restrict__ src, float* __restrict__ rad,
                            float* __restrict__ u3, float* __restrict__ rr) {
  int e = blockIdx.x * blockDim.x + threadIdx.x;
  if (e >= E_) return;
  int nd = dst[e], ns = src[e];
  float dx = pos[ns*3+0] - pos[nd*3+0];
  float dy = pos[ns*3+1] - pos[nd*3+1];
  float dz = pos[ns*3+2] - pos[nd*3+2];
  float r = sqrtf(dx*dx + dy*dy + dz*dz + EPS_);
  float t = r / (1.f + r);
  float b = 1.f - t;
  float tp[K_], bp[K_];
  tp[0] = 1.f; bp[0] = 1.f;
#pragma unroll
  for (int k = 1; k < K_; ++k) { tp[k] = tp[k-1]*t; bp[k] = bp[k-1]*b; }
  float cut = 0.f;
  if (r < CUT_) { float den = (CUT_ - r) * (CUT_ + r); cut = expf(-r*r/den); }
#pragma unroll
  for (int k = 0; k < K_; ++k) rad[(size_t)e*K_ + k] = c_binom[k]*tp[k]*bp[K_-1-k]*cut;
  float invr = 1.f / r;
  u3[(size_t)e*3+0] = dx*invr;
  u3[(size_t)e*3+1] = dy*invr;
  u3[(size_t)e*3+2] = dz*invr;
  rr[e] = r;
}

// ---------------- forward edge pass (full equivariant) ----------------
__global__ __launch_bounds__(256) void edge_fwd_kernel(
    const int* __restrict__ dst, const int* __restrict__ src,
    const float* __restrict__ rad, const float* __restrict__ u3,
    const float* __restrict__ Wb0, const float* __restrict__ Wb1, const float* __restrict__ pw,
    const float* __restrict__ s, const float* __restrict__ v,
    const float* __restrict__ ps, const float* __restrict__ pv,
    float* __restrict__ ys, float* __restrict__ yv,
    float* __restrict__ yps, float* __restrict__ ypv) {
  int gid = blockIdx.x * 256 + threadIdx.x;
  int e = gid >> 5, f = gid & 31;
  int nd = dst[e], ns = src[e];
  float radl = (f < K_) ? rad[(size_t)e*K_ + f] : 0.f;
  float q0 = 0.f, q1 = 0.f;
#pragma unroll
  for (int k = 0; k < K_; ++k) {
    float rk = __shfl(radl, k, 32);
    q0 += rk * Wb0[k*F_ + f];
    q1 += rk * Wb1[k*F_ + f];
  }
  float u0 = u3[(size_t)e*3+0], u1 = u3[(size_t)e*3+1], u2 = u3[(size_t)e*3+2];
  size_t sb = (size_t)ns*F_, vb = (size_t)ns*3*F_;
  float se = s[sb+f], pse = ps[sb+f];
  float ve0 = v[vb+f], ve1 = v[vb+F_+f], ve2 = v[vb+2*F_+f];
  float pve0 = pv[vb+f], pve1 = pv[vb+F_+f], pve2 = pv[vb+2*F_+f];
  float pw0=pw[f],      pw1=pw[F_+f],   pw2=pw[2*F_+f], pw3=pw[3*F_+f], pw4=pw[4*F_+f];
  float pw5=pw[5*F_+f], pw6=pw[6*F_+f], pw7=pw[7*F_+f], pw8=pw[8*F_+f], pw9=pw[9*F_+f];
  float vu  = ve0*u0 + ve1*u1 + ve2*u2;
  float pvu = pve0*u0 + pve1*u1 + pve2*u2;
  float cpu0 = pve1*u2 - pve2*u1, cpu1 = pve2*u0 - pve0*u2, cpu2 = pve0*u1 - pve1*u0;  // pve x u
  float cvu0 = ve1*u2 - ve2*u1,  cvu1 = ve2*u0 - ve0*u2,  cvu2 = ve0*u1 - ve1*u0;      // ve x u
  float ms  = pw0*se*q0  + pw1*vu*q1;
  float mps = pw2*pse*q0 + pw3*pvu*q1;
  float mv0 = pw4*ve0*q0 + (pw5*se*u0 + pw6*cpu0)*q1;
  float mv1 = pw4*ve1*q0 + (pw5*se*u1 + pw6*cpu1)*q1;
  float mv2 = pw4*ve2*q0 + (pw5*se*u2 + pw6*cpu2)*q1;
  float mpv0 = pw7*pve0*q0 + (pw8*pse*u0 + pw9*cvu0)*q1;
  float mpv1 = pw7*pve1*q0 + (pw8*pse*u1 + pw9*cvu1)*q1;
  float mpv2 = pw7*pve2*q0 + (pw8*pse*u2 + pw9*cvu2)*q1;
  size_t db = (size_t)nd*F_, dvb = (size_t)nd*3*F_;
  atomicAdd(&ys[db+f], ms);
  atomicAdd(&yps[db+f], mps);
  atomicAdd(&yv[dvb+f], mv0);       atomicAdd(&yv[dvb+F_+f], mv1);   atomicAdd(&yv[dvb+2*F_+f], mv2);
  atomicAdd(&ypv[dvb+f], mpv0);     atomicAdd(&ypv[dvb+F_+f], mpv1); atomicAdd(&ypv[dvb+2*F_+f], mpv2);
}

// ---------------- forward node MLP (full equivariant) ----------------
__global__ __launch_bounds__(256) void node_fwd_kernel(
    float* __restrict__ s, float* __restrict__ v, float* __restrict__ ps, float* __restrict__ pv,
    const float* __restrict__ ys, const float* __restrict__ yv,
    const float* __restrict__ yps, const float* __restrict__ ypv,
    const float* __restrict__ W1, const float* __restrict__ b1v,
    const float* __restrict__ W2, const float* __restrict__ b2v,
    float* __restrict__ a_s, float* __restrict__ a_v,
    float* __restrict__ a_ps, float* __restrict__ a_pv) {
  int gid = blockIdx.x * 256 + threadIdx.x;
  int n = gid >> 5, f = gid & 31;
  size_t ib = gid;
  size_t vb = (size_t)n*3*F_ + f;
  float y0s  = s[ib] + ys[ib];
  float y0v0 = v[vb] + yv[vb];
  float y0v1 = v[vb+F_] + yv[vb+F_];
  float y0v2 = v[vb+2*F_] + yv[vb+2*F_];
  float y0ps = ps[ib] + yps[ib];
  float y0pv0 = pv[vb] + ypv[vb];
  float y0pv1 = pv[vb+F_] + ypv[vb+F_];
  float y0pv2 = pv[vb+2*F_] + ypv[vb+2*F_];
  const float* W1s = W1; const float* W1v = W1 + F_*F_;
  const float* W1p = W1 + 2*F_*F_; const float* W1q = W1 + 3*F_*F_;
  float as_ = b1v[f], av0=0.f, av1=0.f, av2=0.f, aps_=0.f, apv0=0.f, apv1=0.f, apv2=0.f;
#pragma unroll
  for (int fp = 0; fp < F_; ++fp) {
    float w_s = W1s[fp*F_+f], w_v = W1v[fp*F_+f], w_p = W1p[fp*F_+f], w_q = W1q[fp*F_+f];
    as_  += __shfl(y0s, fp, 32)*w_s;
    av0  += __shfl(y0v0, fp, 32)*w_v;
    av1  += __shfl(y0v1, fp, 32)*w_v;
    av2  += __shfl(y0v2, fp, 32)*w_v;
    aps_ += __shfl(y0ps, fp, 32)*w_p;
    apv0 += __shfl(y0pv0, fp, 32)*w_q;
    apv1 += __shfl(y0pv1, fp, 32)*w_q;
    apv2 += __shfl(y0pv2, fp, 32)*w_q;
  }
  a_s[ib]=as_; a_v[vb]=av0; a_v[vb+F_]=av1; a_v[vb+2*F_]=av2;
  a_ps[ib]=aps_; a_pv[vb]=apv0; a_pv[vb+F_]=apv1; a_pv[vb+2*F_]=apv2;
  float g = sigm(as_);
  float hs=as_*g, hv0=av0*g, hv1=av1*g, hv2=av2*g, hps=aps_*g, hpv0=apv0*g, hpv1=apv1*g, hpv2=apv2*g;
  const float* W2s = W2; const float* W2v = W2 + F_*F_;
  const float* W2p = W2 + 2*F_*F_; const float* W2q = W2 + 3*F_*F_;
  float os_ = b2v[f], ov0=0.f, ov1=0.f, ov2=0.f, ops_=0.f, opv0=0.f, opv1=0.f, opv2=0.f;
#pragma unroll
  for (int fp = 0; fp < F_; ++fp) {
    float w_s = W2s[fp*F_+f], w_v = W2v[fp*F_+f], w_p = W2p[fp*F_+f], w_q = W2q[fp*F_+f];
    os_  += __shfl(hs, fp, 32)*w_s;
    ov0  += __shfl(hv0, fp, 32)*w_v;
    ov1  += __shfl(hv1, fp, 32)*w_v;
    ov2  += __shfl(hv2, fp, 32)*w_v;
    ops_ += __shfl(hps, fp, 32)*w_p;
    opv0 += __shfl(hpv0, fp, 32)*w_q;
    opv1 += __shfl(hpv1, fp, 32)*w_q;
    opv2 += __shfl(hpv2, fp, 32)*w_q;
  }
  s[ib] += os_;
  v[vb] += ov0; v[vb+F_] += ov1; v[vb+2*F_] += ov2;
  ps[ib] += ops_;
  pv[vb] += opv0; pv[vb+F_] += opv1; pv[vb+2*F_] += opv2;
}

// ---------------- forward last (scalar) pass ----------------
__global__ __launch_bounds__(256) void edge_fwd_last_kernel(
    const int* __restrict__ dst, const int* __restrict__ src,
    const float* __restrict__ rad, const float* __restrict__ u3,
    const float* __restrict__ Wb0, const float* __restrict__ Wb1, const float* __restrict__ pwl,
    const float* __restrict__ s, const float* __restrict__ v, float* __restrict__ ys) {
  int gid = blockIdx.x * 256 + threadIdx.x;
  int e = gid >> 5, f = gid & 31;
  int nd = dst[e], ns = src[e];
  float radl = (f < K_) ? rad[(size_t)e*K_ + f] : 0.f;
  float q0 = 0.f, q1 = 0.f;
#pragma unroll
  for (int k = 0; k < K_; ++k) {
    float rk = __shfl(radl, k, 32);
    q0 += rk * Wb0[k*F_ + f];
    q1 += rk * Wb1[k*F_ + f];
  }
  float u0 = u3[(size_t)e*3+0], u1 = u3[(size_t)e*3+1], u2 = u3[(size_t)e*3+2];
  float se = s[(size_t)ns*F_+f];
  size_t vb = (size_t)ns*3*F_;
  float vu = v[vb+f]*u0 + v[vb+F_+f]*u1 + v[vb+2*F_+f]*u2;
  float m = pwl[f]*se*q0 + pwl[F_+f]*vu*q1;
  atomicAdd(&ys[(size_t)nd*F_+f], m);
}

__global__ __launch_bounds__(256) void node_fwd_last_kernel(
    float* __restrict__ s, const float* __restrict__ ys,
    const float* __restrict__ W1, const float* __restrict__ b1v,
    const float* __restrict__ W2, const float* __restrict__ b2v,
    float* __restrict__ a_l, const float* __restrict__ w_out,
    const float* __restrict__ ebias, const int* __restrict__ Z,
    const int* __restrict__ bseg, float* __restrict__ energy) {
  __shared__ float bins[B_];
  int tid = threadIdx.x;
  if (tid < B_) bins[tid] = 0.f;
  __syncthreads();
  int gid = blockIdx.x * 256 + tid;
  int n = gid >> 5, f = gid & 31;
  float y0 = s[gid] + ys[gid];
  float a = b1v[f];
#pragma unroll
  for (int fp = 0; fp < F_; ++fp) a += __shfl(y0, fp, 32) * W1[fp*F_+f];
  a_l[gid] = a;
  float g = sigm(a);
  float h = a * g;
  float o = b2v[f];
#pragma unroll
  for (int fp = 0; fp < F_; ++fp) o += __shfl(h, fp, 32) * W2[fp*F_+f];
  float sn = s[gid] + o;
  s[gid] = sn;
  float c = sn * w_out[f];
#pragma unroll
  for (int off = 16; off > 0; off >>= 1) c += __shfl_xor(c, off, 32);
  if (f == 0) {
    c += ebias[Z[n]];
    atomicAdd(&bins[bseg[n]], c);
  }
  __syncthreads();
  if (tid < B_) atomicAdd(&energy[tid], bins[tid]);
}

// ---------------- backward last (scalar) pass ----------------
__global__ __launch_bounds__(256) void b1_last_kernel(
    float* __restrict__ s, const float* __restrict__ a_l,
    const float* __restrict__ W1, const float* __restrict__ W2, const float* __restrict__ b2v,
    float* __restrict__ Gs, float* __restrict__ ys) {
  int gid = blockIdx.x * 256 + threadIdx.x;
  int f = gid & 31;
  float a = a_l[gid];
  float g = sigm(a);
  float h = a * g;
  float o = b2v[f];
#pragma unroll
  for (int fp = 0; fp < F_; ++fp) o += __shfl(h, fp, 32) * W2[fp*F_+f];
  s[gid] -= o;                       // reconstruct s_4
  float gso = Gs[gid];
  float gh = 0.f;
#pragma unroll
  for (int fp = 0; fp < F_; ++fp) gh += __shfl(gso, fp, 32) * W2[f*F_+fp];
  float ga = gh * (g + a*g*(1.f - g));
  float gy = 0.f;
#pragma unroll
  for (int fp = 0; fp < F_; ++fp) gy += __shfl(ga, fp, 32) * W1[f*F_+fp];
  ys[gid] = gy;
  Gs[gid] = gso + gy;
}

__global__ __launch_bounds__(256) void b2_last_kernel(
    const int* __restrict__ dst, const int* __restrict__ src,
    const float* __restrict__ rad, const float* __restrict__ u3,
    const float* __restrict__ Wb0, const float* __restrict__ Wb1, const float* __restrict__ pwl,
    const float* __restrict__ s, const float* __restrict__ v, const float* __restrict__ ysg,
    float* __restrict__ Gs, float* __restrict__ Gv,
    float* __restrict__ grad_rad, float* __restrict__ grad_u) {
  int gid = blockIdx.x * 256 + threadIdx.x;
  int e = gid >> 5, f = gid & 31;
  int nd = dst[e], ns = src[e];
  float radl = (f < K_) ? rad[(size_t)e*K_ + f] : 0.f;
  float q0 = 0.f, q1 = 0.f;
#pragma unroll
  for (int k = 0; k < K_; ++k) {
    float rk = __shfl(radl, k, 32);
    q0 += rk * Wb0[k*F_ + f];
    q1 += rk * Wb1[k*F_ + f];
  }
  float u0 = u3[(size_t)e*3+0], u1 = u3[(size_t)e*3+1], u2 = u3[(size_t)e*3+2];
  float gm = ysg[(size_t)nd*F_+f];
  float se = s[(size_t)ns*F_+f];
  size_t vb = (size_t)ns*3*F_;
  float ve0 = v[vb+f], ve1 = v[vb+F_+f], ve2 = v[vb+2*F_+f];
  float p0 = pwl[f], p1 = pwl[F_+f];
  atomicAdd(&Gs[(size_t)ns*F_+f], p0*q0*gm);
  float t1 = p1*q1*gm;
  atomicAdd(&Gv[vb+f], t1*u0);
  atomicAdd(&Gv[vb+F_+f], t1*u1);
  atomicAdd(&Gv[vb+2*F_+f], t1*u2);
  float vu = ve0*u0 + ve1*u1 + ve2*u2;
  float gq0 = p0*se*gm;
  float gq1 = p1*vu*gm;
  float keep = 0.f;
#pragma unroll
  for (int k = 0; k < K_; ++k) {
    float pr = gq0*Wb0[k*F_+f] + gq1*Wb1[k*F_+f];
#pragma unroll
    for (int off = 16; off > 0; off >>= 1) pr += __shfl_xor(pr, off, 32);
    if (f == k) keep = pr;
  }
  if (f < K_) grad_rad[(size_t)e*K_+f] += keep;
  float g0 = t1*ve0, g1 = t1*ve1, g2 = t1*ve2;
#pragma unroll
  for (int off = 16; off > 0; off >>= 1) {
    g0 += __shfl_xor(g0, off, 32);
    g1 += __shfl_xor(g1, off, 32);
    g2 += __shfl_xor(g2, off, 32);
  }
  if (f < 3) grad_u[(size_t)e*3+f] += (f==0 ? g0 : (f==1 ? g1 : g2));
}

// ---------------- backward node MLP (full equivariant) ----------------
__global__ __launch_bounds__(256) void b1_kernel(
    float* __restrict__ s, float* __restrict__ v, float* __restrict__ ps, float* __restrict__ pv,
    const float* __restrict__ a_s, const float* __restrict__ a_v,
    const float* __restrict__ a_ps, const float* __restrict__ a_pv,
    const float* __restrict__ W1, const float* __restrict__ W2, const float* __restrict__ b2v,
    float* __restrict__ Gs, float* __restrict__ Gv, float* __restrict__ Gps, float* __restrict__ Gpv,
    float* __restrict__ ys, float* __restrict__ yv, float* __restrict__ yps, float* __restrict__ ypv) {
  int gid = blockIdx.x * 256 + threadIdx.x;
  int n = gid >> 5, f = gid & 31;
  size_t ib = gid;
  size_t vb = (size_t)n*3*F_ + f;
  float as_ = a_s[ib], av0 = a_v[vb], av1 = a_v[vb+F_], av2 = a_v[vb+2*F_];
  float aps_ = a_ps[ib], apv0 = a_pv[vb], apv1 = a_pv[vb+F_], apv2 = a_pv[vb+2*F_];
  float g = sigm(as_);
  float gp = g * (1.f - g);
  float hs=as_*g, hv0=av0*g, hv1=av1*g, hv2=av2*g, hps=aps_*g, hpv0=apv0*g, hpv1=apv1*g, hpv2=apv2*g;
  const float* W2s = W2; const float* W2v = W2 + F_*F_;
  const float* W2p = W2 + 2*F_*F_; const float* W2q = W2 + 3*F_*F_;
  const float* W1s = W1; const float* W1v = W1 + F_*F_;
  const float* W1p = W1 + 2*F_*F_; const float* W1q = W1 + 3*F_*F_;
  float os_ = b2v[f], ov0=0.f, ov1=0.f, ov2=0.f, ops_=0.f, opv0=0.f, opv1=0.f, opv2=0.f;
#pragma unroll
  for (int fp = 0; fp < F_; ++fp) {
    float w_s = W2s[fp*F_+f], w_v = W2v[fp*F_+f], w_p = W2p[fp*F_+f], w_q = W2q[fp*F_+f];
    os_  += __shfl(hs, fp, 32)*w_s;
    ov0  += __shfl(hv0, fp, 32)*w_v;
    ov1  += __shfl(hv1, fp, 32)*w_v;
    ov2  += __shfl(hv2, fp, 32)*w_v;
    ops_ += __shfl(hps, fp, 32)*w_p;
    opv0 += __shfl(hpv0, fp, 32)*w_q;
    opv1 += __shfl(hpv1, fp, 32)*w_q;
    opv2 += __shfl(hpv2, fp, 32)*w_q;
  }
  s[ib] -= os_;
  v[vb] -= ov0; v[vb+F_] -= ov1; v[vb+2*F_] -= ov2;
  ps[ib] -= ops_;
  pv[vb] -= opv0; pv[vb+F_] -= opv1; pv[vb+2*F_] -= opv2;
  float GsV = Gs[ib], Gv0 = Gv[vb], Gv1 = Gv[vb+F_], Gv2 = Gv[vb+2*F_];
  float GpsV = Gps[ib], Gq0 = Gpv[vb], Gq1 = Gpv[vb+F_], Gq2 = Gpv[vb+2*F_];
  float ghs=0.f, ghv0=0.f, ghv1=0.f, ghv2=0.f, ghps=0.f, ghpv0=0.f, ghpv1=0.f, ghpv2=0.f;
#pragma unroll
  for (int fp = 0; fp < F_; ++fp) {
    float w_s = W2s[f*F_+fp], w_v = W2v[f*F_+fp], w_p = W2p[f*F_+fp], w_q = W2q[f*F_+fp];
    ghs   += __shfl(GsV, fp, 32)*w_s;
    ghv0  += __shfl(Gv0, fp, 32)*w_v;
    ghv1  += __shfl(Gv1, fp, 32)*w_v;
    ghv2  += __shfl(Gv2, fp, 32)*w_v;
    ghps  += __shfl(GpsV, fp, 32)*w_p;
    ghpv0 += __shfl(Gq0, fp, 32)*w_q;
    ghpv1 += __shfl(Gq1, fp, 32)*w_q;
    ghpv2 += __shfl(Gq2, fp, 32)*w_q;
  }
  float gas = ghs*g + (ghs*as_ + ghv0*av0 + ghv1*av1 + ghv2*av2 + ghps*aps_
                       + ghpv0*apv0 + ghpv1*apv1 + ghpv2*apv2) * gp;
  float gav0 = ghv0*g, gav1 = ghv1*g, gav2 = ghv2*g;
  float gaps = ghps*g;
  float gapv0 = ghpv0*g, gapv1 = ghpv1*g, gapv2 = ghpv2*g;
  float gys_=0.f, gyv0=0.f, gyv1=0.f, gyv2=0.f, gyps_=0.f, gypv0=0.f, gypv1=0.f, gypv2=0.f;
#pragma unroll
  for (int fp = 0; fp < F_; ++fp) {
    float w_s = W1s[f*F_+fp], w_v = W1v[f*F_+fp], w_p = W1p[f*F_+fp], w_q = W1q[f*F_+fp];
    gys_  += __shfl(gas, fp, 32)*w_s;
    gyv0  += __shfl(gav0, fp, 32)*w_v;
    gyv1  += __shfl(gav1, fp, 32)*w_v;
    gyv2  += __shfl(gav2, fp, 32)*w_v;
    gyps_ += __shfl(gaps, fp, 32)*w_p;
    gypv0 += __shfl(gapv0, fp, 32)*w_q;
    gypv1 += __shfl(gapv1, fp, 32)*w_q;
    gypv2 += __shfl(gapv2, fp, 32)*w_q;
  }
  ys[ib]=gys_; yv[vb]=gyv0; yv[vb+F_]=gyv1; yv[vb+2*F_]=gyv2;
  yps[ib]=gyps_; ypv[vb]=gypv0; ypv[vb+F_]=gypv1; ypv[vb+2*F_]=gypv2;
  Gs[ib]=GsV+gys_; Gv[vb]=Gv0+gyv0; Gv[vb+F_]=Gv1+gyv1; Gv[vb+2*F_]=Gv2+gyv2;
  Gps[ib]=GpsV+gyps_; Gpv[vb]=Gq0+gypv0; Gpv[vb+F_]=Gq1+gypv1; Gpv[vb+2*F_]=Gq2+gypv2;
}

// ---------------- backward edge pass (full equivariant) ----------------
__global__ __launch_bounds__(256) void b2_kernel(
    const int* __restrict__ dst, const int* __restrict__ src,
    const float* __restrict__ rad, const float* __restrict__ u3,
    const float* __restrict__ Wb0, const float* __restrict__ Wb1, const float* __restrict__ pw,
    const float* __restrict__ s, const float* __restrict__ v,
    const float* __restrict__ ps, const float* __restrict__ pv,
    const float* __restrict__ ys, const float* __restrict__ yv,
    const float* __restrict__ yps, const float* __restrict__ ypv,
    float* __restrict__ Gs, float* __restrict__ Gv, float* __restrict__ Gps, float* __restrict__ Gpv,
    float* __restrict__ grad_rad, float* __restrict__ grad_u) {
  int gid = blockIdx.x * 256 + threadIdx.x;
  int e = gid >> 5, f = gid & 31;
  int nd = dst[e], ns = src[e];
  float radl = (f < K_) ? rad[(size_t)e*K_ + f] : 0.f;
  float q0 = 0.f, q1 = 0.f;
#pragma unroll
  for (int k = 0; k < K_; ++k) {
    float rk = __shfl(radl, k, 32);
    q0 += rk * Wb0[k*F_ + f];
    q1 += rk * Wb1[k*F_ + f];
  }
  float u0 = u3[(size_t)e*3+0], u1 = u3[(size_t)e*3+1], u2 = u3[(size_t)e*3+2];
  size_t db = (size_t)nd*F_, dvb = (size_t)nd*3*F_;
  float gms = ys[db+f];
  float gmv0 = yv[dvb+f], gmv1 = yv[dvb+F_+f], gmv2 = yv[dvb+2*F_+f];
  float gmps = yps[db+f];
  float gmpv0 = ypv[dvb+f], gmpv1 = ypv[dvb+F_+f], gmpv2 = ypv[dvb+2*F_+f];
  size_t sb = (size_t)ns*F_, svb = (size_t)ns*3*F_;
  float se = s[sb+f], pse = ps[sb+f];
  float ve0 = v[svb+f], ve1 = v[svb+F_+f], ve2 = v[svb+2*F_+f];
  float pve0 = pv[svb+f], pve1 = pv[svb+F_+f], pve2 = pv[svb+2*F_+f];
  float pw0=pw[f],      pw1=pw[F_+f],   pw2=pw[2*F_+f], pw3=pw[3*F_+f], pw4=pw[4*F_+f];
  float pw5=pw[5*F_+f], pw6=pw[6*F_+f], pw7=pw[7*F_+f], pw8=pw[8*F_+f], pw9=pw[9*F_+f];
  float udgmv  = u0*gmv0 + u1*gmv1 + u2*gmv2;
  float udgmpv = u0*gmpv0 + u1*gmpv1 + u2*gmpv2;
  float uxgmpv0 = u1*gmpv2 - u2*gmpv1, uxgmpv1 = u2*gmpv0 - u0*gmpv2, uxgmpv2 = u0*gmpv1 - u1*gmpv0;
  float uxgmv0  = u1*gmv2 - u2*gmv1,   uxgmv1  = u2*gmv0 - u0*gmv2,   uxgmv2  = u0*gmv1 - u1*gmv0;
  // source-state grads (messages are linear in source state)
  float gse  = pw0*q0*gms  + pw5*q1*udgmv;
  float gpse = pw2*q0*gmps + pw8*q1*udgmpv;
  float gve0 = pw1*u0*q1*gms + pw4*q0*gmv0 + pw9*q1*uxgmpv0;
  float gve1 = pw1*u1*q1*gms + pw4*q0*gmv1 + pw9*q1*uxgmpv1;
  float gve2 = pw1*u2*q1*gms + pw4*q0*gmv2 + pw9*q1*uxgmpv2;
  float gpve0 = pw3*u0*q1*gmps + pw7*q0*gmpv0 + pw6*q1*uxgmv0;
  float gpve1 = pw3*u1*q1*gmps + pw7*q0*gmpv1 + pw6*q1*uxgmv1;
  float gpve2 = pw3*u2*q1*gmps + pw7*q0*gmpv2 + pw6*q1*uxgmv2;
  atomicAdd(&Gs[sb+f], gse);
  atomicAdd(&Gps[sb+f], gpse);
  atomicAdd(&Gv[svb+f], gve0);   atomicAdd(&Gv[svb+F_+f], gve1);   atomicAdd(&Gv[svb+2*F_+f], gve2);
  atomicAdd(&Gpv[svb+f], gpve0); atomicAdd(&Gpv[svb+F_+f], gpve1); atomicAdd(&Gpv[svb+2*F_+f], gpve2);
  // basis grads
  float vu  = ve0*u0 + ve1*u1 + ve2*u2;
  float pvu = pve0*u0 + pve1*u1 + pve2*u2;
  float cpu0 = pve1*u2 - pve2*u1, cpu1 = pve2*u0 - pve0*u2, cpu2 = pve0*u1 - pve1*u0;  // pve x u
  float cvu0 = ve1*u2 - ve2*u1,  cvu1 = ve2*u0 - ve0*u2,  cvu2 = ve0*u1 - ve1*u0;      // ve x u
  float gq0 = pw0*se*gms + pw2*pse*gmps
            + pw4*(ve0*gmv0 + ve1*gmv1 + ve2*gmv2)
            + pw7*(pve0*gmpv0 + pve1*gmpv1 + pve2*gmpv2);
  float gq1 = pw1*vu*gms + pw3*pvu*gmps + pw5*se*udgmv
            + pw6*(cpu0*gmv0 + cpu1*gmv1 + cpu2*gmv2)
            + pw8*pse*udgmpv
            + pw9*(cvu0*gmpv0 + cvu1*gmpv1 + cvu2*gmpv2);
  float gmvxpve0 = gmv1*pve2 - gmv2*pve1, gmvxpve1 = gmv2*pve0 - gmv0*pve2, gmvxpve2 = gmv0*pve1 - gmv1*pve0;
  float gmpvxve0 = gmpv1*ve2 - gmpv2*ve1, gmpvxve1 = gmpv2*ve0 - gmpv0*ve2, gmpvxve2 = gmpv0*ve1 - gmpv1*ve0;
  float gu0 = q1*(pw1*gms*ve0 + pw3*gmps*pve0 + pw5*se*gmv0 + pw6*gmvxpve0 + pw8*pse*gmpv0 + pw9*gmpvxve0);
  float gu1 = q1*(pw1*gms*ve1 + pw3*gmps*pve1 + pw5*se*gmv1 + pw6*gmvxpve1 + pw8*pse*gmpv1 + pw9*gmpvxve1);
  float gu2 = q1*(pw1*gms*ve2 + pw3*gmps*pve2 + pw5*se*gmv2 + pw6*gmvxpve2 + pw8*pse*gmpv2 + pw9*gmpvxve2);
  float keep = 0.f;
#pragma unroll
  for (int k = 0; k < K_; ++k) {
    float pr = gq0*Wb0[k*F_+f] + gq1*Wb1[k*F_+f];
#pragma unroll
    for (int off = 16; off > 0; off >>= 1) pr += __shfl_xor(pr, off, 32);
    if (f == k) keep = pr;
  }
  if (f < K_) grad_rad[(size_t)e*K_+f] += keep;
#pragma unroll
  for (int off = 16; off > 0; off >>= 1) {
    gu0 += __shfl_xor(gu0, off, 32);
    gu1 += __shfl_xor(gu1, off, 32);
    gu2 += __shfl_xor(gu2, off, 32);
  }
  if (f < 3) grad_u[(size_t)e*3+f] += (f==0 ? gu0 : (f==1 ? gu1 : gu2));
}

// ---------------- basis backward: (grad_rad, grad_u) -> forces ----------------
__global__ void basis_bwd_kernel(const int* __restrict__ dst, const int* __restrict__ src,
                                 const float* __restrict__ rr, const float* __restrict__ u3,
                                 const float* __restrict__ grad_rad, const float* __restrict__ grad_u,
                                 float* __restrict__ forces) {
  int e = blockIdx.x * blockDim.x + threadIdx.x;
  if (e >= E_) return;
  float r = rr[e];
  float u0 = u3[(size_t)e*3+0], u1 = u3[(size_t)e*3+1], u2 = u3[(size_t)e*3+2];
  float t = r / (1.f + r);
  float b = 1.f - t;
  float tp[K_], bp[K_];
  tp[0] = 1.f; bp[0] = 1.f;
#pragma unroll
  for (int k = 1; k < K_; ++k) { tp[k] = tp[k-1]*t; bp[k] = bp[k-1]*b; }
  float cut = 0.f, dcut = 0.f;
  if (r < CUT_) {
    float den = (CUT_ - r) * (CUT_ + r);
    cut = expf(-r*r/den);
    dcut = (cut > 0.f) ? cut * (-2.f*r*CUT_*CUT_/(den*den)) : 0.f;
  }
  float inv1pr = 1.f / (1.f + r);
  float dtdr = inv1pr * inv1pr;
  float gr = 0.f;
#pragma unroll
  for (int k = 0; k < K_; ++k) {
    float rrk = c_binom[k]*tp[k]*bp[K_-1-k];
    float d1 = (k > 0) ? k*tp[k-1]*bp[K_-1-k] : 0.f;
    float d2 = (k < K_-1) ? (K_-1-k)*tp[k]*bp[K_-2-k] : 0.f;
    float drdt = c_binom[k]*(d1 - d2);
    gr += grad_rad[(size_t)e*K_+k] * (drdt*dtdr*cut + rrk*dcut);
  }
  float g0 = grad_u[(size_t)e*3+0], g1 = grad_u[(size_t)e*3+1], g2 = grad_u[(size_t)e*3+2];
  float gdu = g0*u0 + g1*u1 + g2*u2;
  float invr = 1.f / r;
  float gd0 = gr*u0 + (g0 - gdu*u0)*invr;
  float gd1 = gr*u1 + (g1 - gdu*u1)*invr;
  float gd2 = gr*u2 + (g2 - gdu*u2)*invr;
  int ns = src[e], nd = dst[e];
  atomicAdd(&forces[(size_t)ns*3+0], gd0);
  atomicAdd(&forces[(size_t)ns*3+1], gd1);
  atomicAdd(&forces[(size_t)ns*3+2], gd2);
  atomicAdd(&forces[(size_t)nd*3+0], -gd0);
  atomicAdd(&forces[(size_t)nd*3+1], -gd1);
  atomicAdd(&forces[(size_t)nd*3+2], -gd2);
}

// ---------------- host launcher ----------------
extern "C" void kernel_launch(void* const* d_in, const int* in_sizes, int n_in,
                              void* d_out, int out_size, void* d_ws, size_t ws_size,
                              hipStream_t stream) {
  const int*   Z     = (const int*)d_in[0];
  const float* pos   = (const float*)d_in[1];
  const int*   dst   = (const int*)d_in[2];
  const int*   src   = (const int*)d_in[3];
  const int*   bseg  = (const int*)d_in[4];
  const float* embed = (const float*)d_in[6];
  const float* Wb0   = (const float*)d_in[7];
  const float* Wb1   = (const float*)d_in[8];
  const float* pw    = (const float*)d_in[9];
  const float* Wd1   = (const float*)d_in[10];
  const float* bd1   = (const float*)d_in[11];
  const float* Wd2   = (const float*)d_in[12];
  const float* bd2   = (const float*)d_in[13];
  const float* Wb0l  = (const float*)d_in[14];
  const float* Wb1l  = (const float*)d_in[15];
  const float* pwl   = (const float*)d_in[16];
  const float* Wd1l  = (const float*)d_in[17];
  const float* bd1l  = (const float*)d_in[18];
  const float* Wd2l  = (const float*)d_in[19];
  const float* bd2l  = (const float*)d_in[20];
  const float* w_out = (const float*)d_in[21];
  const float* ebias = (const float*)d_in[22];

  float* out = (float*)d_out;
  float* energy = out;          // (B,)
  float* forces = out + B_;     // (N,3)

  // workspace from static device symbol (d_ws size is unknown/too small)
  float* ws = nullptr;
  (void)hipGetSymbolAddress((void**)&ws, HIP_SYMBOL(g_ws));

  const size_t NF = (size_t)N_ * F_;
  const size_t NV = (size_t)N_ * 3 * F_;
  float* rad      = ws;                       // E*K
  float* u3       = rad + (size_t)E_*K_;      // E*3
  float* rr       = u3 + (size_t)E_*3;        // E
  float* s        = rr + E_;                  // N*F
  float* v        = s + NF;                   // N*3F
  float* ps       = v + NV;                   // N*F
  float* pv       = ps + NF;                  // N*3F
  float* ys       = pv + NV;                  // N*F
  float* yv       = ys + NF;                  // N*3F
  float* yps      = yv + NV;                  // N*F
  float* ypv      = yps + NF;                 // N*3F
  float* Gs       = ypv + NV;                 // N*F
  float* Gv       = Gs + NF;                  // N*3F
  float* Gps      = Gv + NV;                  // N*F
  float* Gpv      = Gps + NF;                 // N*3F
  float* grad_rad = Gpv + NV;                 // E*K
  float* grad_u   = grad_rad + (size_t)E_*K_; // E*3
  float* a_s      = grad_u + (size_t)E_*3;    // 4*N*F
  float* a_v      = a_s + 4*NF;               // 4*N*3F
  float* a_ps     = a_v + 4*NV;               // 4*N*F
  float* a_pv     = a_ps + 4*NF;              // 4*N*3F
  float* a_l      = a_pv + 4*NV;              // N*F

  const int TB = 256;
  const int nodeBlocks = (int)(NF / TB);       // 6250
  const int edgeBlocks = (int)((size_t)E_*32 / TB);  // 50000
  const int eThreadBlocks = (E_ + TB - 1) / TB;

  // init state: s = embed[Z], v/ps/pv = 0 (contiguous 7*NF)
  fill_kernel<<<2048, TB, 0, stream>>>(v, 7*NF, 0.f);
  init_embed_kernel<<<nodeBlocks, TB, 0, stream>>>(s, embed, Z);
  geom_kernel<<<eThreadBlocks, TB, 0, stream>>>(pos, dst, src, rad, u3, rr);

  // 4 full equivariant passes
  for (int i = 0; i < 4; ++i) {
    fill_kernel<<<2048, TB, 0, stream>>>(ys, 8*NF, 0.f);  // ys..ypv contiguous
    edge_fwd_kernel<<<edgeBlocks, TB, 0, stream>>>(
        dst, src, rad, u3,
        Wb0 + (size_t)i*K_*F_, Wb1 + (size_t)i*K_*F_, pw + (size_t)i*10*F_,
        s, v, ps, pv, ys, yv, yps, ypv);
    node_fwd_kernel<<<nodeBlocks, TB, 0, stream>>>(
        s, v, ps, pv, ys, yv, yps, ypv,
        Wd1 + (size_t)i*4*F_*F_, bd1 + (size_t)i*F_,
        Wd2 + (size_t)i*4*F_*F_, bd2 + (size_t)i*F_,
        a_s + i*NF, a_v + i*NV, a_ps + i*NF, a_pv + i*NV);
  }

  // zero outputs (energy + forces), then last scalar pass
  fill_kernel<<<592, TB, 0, stream>>>(out, (size_t)(B_ + N_*3), 0.f);
  fill_kernel<<<2048, TB, 0, stream>>>(ys, NF, 0.f);
  edge_fwd_last_kernel<<<edgeBlocks, TB, 0, stream>>>(
      dst, src, rad, u3, Wb0l, Wb1l, pwl, s, v, ys);
  node_fwd_last_kernel<<<nodeBlocks, TB, 0, stream>>>(
      s, ys, Wd1l, bd1l, Wd2l, bd2l, a_l, w_out, ebias, Z, bseg, energy);

  // backward init: Gs = -w_out, Gv/Gps/Gpv = 0, grad_rad/grad_u = 0
  init_gs_kernel<<<nodeBlocks, TB, 0, stream>>>(Gs, w_out);
  fill_kernel<<<2048, TB, 0, stream>>>(Gv, 7*NF, 0.f);
  fill_kernel<<<2048, TB, 0, stream>>>(grad_rad, (size_t)E_*(K_+3), 0.f);

  // last pass backward
  b1_last_kernel<<<nodeBlocks, TB, 0, stream>>>(s, a_l, Wd1l, Wd2l, bd2l, Gs, ys);
  b2_last_kernel<<<edgeBlocks, TB, 0, stream>>>(
      dst, src, rad, u3, Wb0l, Wb1l, pwl, s, v, ys, Gs, Gv, grad_rad, grad_u);

  // 4 full passes backward (state reconstructed in place from stored a_*)
  for (int i = 3; i >= 0; --i) {
    b1_kernel<<<nodeBlocks, TB, 0, stream>>>(
        s, v, ps, pv,
        a_s + i*NF, a_v + i*NV, a_ps + i*NF, a_pv + i*NV,
        Wd1 + (size_t)i*4*F_*F_, Wd2 + (size_t)i*4*F_*F_, bd2 + (size_t)i*F_,
        Gs, Gv, Gps, Gpv, ys, yv, yps, ypv);
    b2_kernel<<<edgeBlocks, TB, 0, stream>>>(
        dst, src, rad, u3,
        Wb0 + (size_t)i*K_*F_, Wb1 + (size_t)i*K_*F_, pw + (size_t)i*10*F_,
        s, v, ps, pv, ys, yv, yps, ypv, Gs, Gv, Gps, Gpv, grad_rad, grad_u);
  }

  // basis backward -> forces
  basis_bwd_kernel<<<eThreadBlocks, TB, 0, stream>>>(
      dst, src, rr, u3, grad_rad, grad_u, forces);
}

// Round 3
// 5032.564 us; speedup vs baseline: 1.2490x; 1.2490x over previous
//
#include <hip/hip_runtime.h>
#include <math.h>

namespace {
constexpr int N_ = 50000;
constexpr int E_ = 400000;
constexpr int F_ = 32;
constexpr int K_ = 16;
constexpr int B_ = 10;
constexpr float CUT_ = 10.0f;
constexpr float EPS_ = 1e-8f;
constexpr size_t WS_FLOATS = 107900016;  // floats + int region (see layout)
}

// Static device scratch (d_ws size unknown). ~432 MB BSS.
__device__ float g_ws[WS_FLOATS];

__constant__ float c_binom[K_] = {1.f,15.f,105.f,455.f,1365.f,3003.f,5005.f,6435.f,
                                  6435.f,5005.f,3003.f,1365.f,455.f,105.f,15.f,1.f};

__device__ __forceinline__ float sigm(float x) { return 1.f / (1.f + expf(-x)); }

// ---------------- utility fills ----------------
__global__ void fill_kernel(float* __restrict__ p, size_t n, float v) {
  size_t i = (size_t)blockIdx.x * blockDim.x + threadIdx.x;
  size_t st = (size_t)gridDim.x * blockDim.x;
  for (; i < n; i += st) p[i] = v;
}

__global__ void fill_int_kernel(int* __restrict__ p, size_t n, int v) {
  size_t i = (size_t)blockIdx.x * blockDim.x + threadIdx.x;
  size_t st = (size_t)gridDim.x * blockDim.x;
  for (; i < n; i += st) p[i] = v;
}

__global__ void init_embed_kernel(float* __restrict__ s, const float* __restrict__ embed,
                                  const int* __restrict__ Z) {
  int gid = blockIdx.x * blockDim.x + threadIdx.x;
  int n = gid >> 5, f = gid & 31;
  s[gid] = embed[Z[n] * F_ + f];
}

__global__ void init_gs_kernel(float* __restrict__ Gs, const float* __restrict__ w_out) {
  int gid = blockIdx.x * blockDim.x + threadIdx.x;
  Gs[gid] = -w_out[gid & 31];
}

// ---------------- CSR build ----------------
__global__ void hist_kernel(const int* __restrict__ dst, const int* __restrict__ src,
                            int* __restrict__ cntd, int* __restrict__ cnts) {
  int e = blockIdx.x * blockDim.x + threadIdx.x;
  if (e < E_) { atomicAdd(&cntd[dst[e]], 1); atomicAdd(&cnts[src[e]], 1); }
}

__global__ __launch_bounds__(1024) void scan_kernel(
    const int* __restrict__ cntd, const int* __restrict__ cnts,
    int* __restrict__ offd, int* __restrict__ offs) {
  const int* cnt = blockIdx.x ? cnts : cntd;
  int* off = blockIdx.x ? offs : offd;
  __shared__ int part[1024];
  int tid = threadIdx.x;
  const int CH = (N_ + 1023) / 1024;  // 49
  int base = tid * CH;
  int sum = 0;
  for (int i = 0; i < CH; ++i) { int j = base + i; if (j < N_) sum += cnt[j]; }
  part[tid] = sum; __syncthreads();
  for (int d = 1; d < 1024; d <<= 1) {
    int t = (tid >= d) ? part[tid - d] : 0; __syncthreads();
    part[tid] += t; __syncthreads();
  }
  int run = (tid == 0) ? 0 : part[tid - 1];
  for (int i = 0; i < CH; ++i) {
    int j = base + i;
    if (j <= N_) { off[j] = run; if (j < N_) run += cnt[j]; }
  }
}

__global__ void cursor_init_kernel(const int* __restrict__ offd, const int* __restrict__ offs,
                                   int* __restrict__ curd, int* __restrict__ curs) {
  int i = blockIdx.x * blockDim.x + threadIdx.x;
  if (i < N_) { curd[i] = offd[i]; curs[i] = offs[i]; }
}

__global__ void scatter_kernel(const int* __restrict__ dst, const int* __restrict__ src,
                               int* __restrict__ curd, int* __restrict__ curs,
                               int* __restrict__ permd, int* __restrict__ perms) {
  int e = blockIdx.x * blockDim.x + threadIdx.x;
  if (e < E_) {
    permd[atomicAdd(&curd[dst[e]], 1)] = e;
    perms[atomicAdd(&curs[src[e]], 1)] = e;
  }
}

// ---------------- geometry / basis ----------------
__global__ void geom_kernel(const float* __restrict__ pos, const int* __restrict__ dst,
                            const int* __restrict__ src, float* __restrict__ rad,
                            float* __restrict__ u3, float* __restrict__ rr) {
  int e = blockIdx.x * blockDim.x + threadIdx.x;
  if (e >= E_) return;
  int nd = dst[e], ns = src[e];
  float dx = pos[ns*3+0] - pos[nd*3+0];
  float dy = pos[ns*3+1] - pos[nd*3+1];
  float dz = pos[ns*3+2] - pos[nd*3+2];
  float r = sqrtf(dx*dx + dy*dy + dz*dz + EPS_);
  float t = r / (1.f + r);
  float b = 1.f - t;
  float tp[K_], bp[K_];
  tp[0] = 1.f; bp[0] = 1.f;
#pragma unroll
  for (int k = 1; k < K_; ++k) { tp[k] = tp[k-1]*t; bp[k] = bp[k-1]*b; }
  float cut = 0.f;
  if (r < CUT_) { float den = (CUT_ - r) * (CUT_ + r); cut = expf(-r*r/den); }
#pragma unroll
  for (int k = 0; k < K_; ++k) rad[(size_t)e*K_ + k] = c_binom[k]*tp[k]*bp[K_-1-k]*cut;
  float invr = 1.f / r;
  u3[(size_t)e*3+0] = dx*invr;
  u3[(size_t)e*3+1] = dy*invr;
  u3[(size_t)e*3+2] = dz*invr;
  rr[e] = r;
}

// ---------------- forward edge pass: warp per dst node ----------------
__global__ __launch_bounds__(256) void edge_fwd_csr(
    const int* __restrict__ dst_off, const int* __restrict__ dst_perm,
    const int* __restrict__ src,
    const float* __restrict__ rad, const float* __restrict__ u3,
    const float* __restrict__ Wb0, const float* __restrict__ Wb1, const float* __restrict__ pw,
    const float* __restrict__ s, const float* __restrict__ v,
    const float* __restrict__ ps, const float* __restrict__ pv,
    float* __restrict__ ys, float* __restrict__ yv,
    float* __restrict__ yps, float* __restrict__ ypv) {
  int gid = blockIdx.x * 256 + threadIdx.x;
  int n = gid >> 5, f = gid & 31;
  float wb0[K_], wb1[K_];
#pragma unroll
  for (int k = 0; k < K_; ++k) { wb0[k] = Wb0[k*F_+f]; wb1[k] = Wb1[k*F_+f]; }
  float pw0=pw[f],      pw1=pw[F_+f],   pw2=pw[2*F_+f], pw3=pw[3*F_+f], pw4=pw[4*F_+f];
  float pw5=pw[5*F_+f], pw6=pw[6*F_+f], pw7=pw[7*F_+f], pw8=pw[8*F_+f], pw9=pw[9*F_+f];
  float ms=0.f, mps=0.f, mv0=0.f, mv1=0.f, mv2=0.f, mpv0=0.f, mpv1=0.f, mpv2=0.f;
  int j0 = dst_off[n], j1 = dst_off[n+1];
  for (int j = j0; j < j1; ++j) {
    int e = dst_perm[j];
    int ns = src[e];
    float radl = (f < K_) ? rad[(size_t)e*K_ + f] : 0.f;
    float q0 = 0.f, q1 = 0.f;
#pragma unroll
    for (int k = 0; k < K_; ++k) {
      float rk = __shfl(radl, k, 32);
      q0 += rk * wb0[k];
      q1 += rk * wb1[k];
    }
    float u0 = u3[(size_t)e*3+0], u1 = u3[(size_t)e*3+1], u2 = u3[(size_t)e*3+2];
    size_t sb = (size_t)ns*F_, vb = (size_t)ns*3*F_;
    float se = s[sb+f], pse = ps[sb+f];
    float ve0 = v[vb+f], ve1 = v[vb+F_+f], ve2 = v[vb+2*F_+f];
    float pve0 = pv[vb+f], pve1 = pv[vb+F_+f], pve2 = pv[vb+2*F_+f];
    float vu  = ve0*u0 + ve1*u1 + ve2*u2;
    float pvu = pve0*u0 + pve1*u1 + pve2*u2;
    float cpu0 = pve1*u2 - pve2*u1, cpu1 = pve2*u0 - pve0*u2, cpu2 = pve0*u1 - pve1*u0;
    float cvu0 = ve1*u2 - ve2*u1,  cvu1 = ve2*u0 - ve0*u2,  cvu2 = ve0*u1 - ve1*u0;
    ms  += pw0*se*q0  + pw1*vu*q1;
    mps += pw2*pse*q0 + pw3*pvu*q1;
    mv0 += pw4*ve0*q0 + (pw5*se*u0 + pw6*cpu0)*q1;
    mv1 += pw4*ve1*q0 + (pw5*se*u1 + pw6*cpu1)*q1;
    mv2 += pw4*ve2*q0 + (pw5*se*u2 + pw6*cpu2)*q1;
    mpv0 += pw7*pve0*q0 + (pw8*pse*u0 + pw9*cvu0)*q1;
    mpv1 += pw7*pve1*q0 + (pw8*pse*u1 + pw9*cvu1)*q1;
    mpv2 += pw7*pve2*q0 + (pw8*pse*u2 + pw9*cvu2)*q1;
  }
  size_t db = (size_t)n*F_, dvb = (size_t)n*3*F_;
  ys[db+f] = ms;
  yps[db+f] = mps;
  yv[dvb+f] = mv0;   yv[dvb+F_+f] = mv1;   yv[dvb+2*F_+f] = mv2;
  ypv[dvb+f] = mpv0; ypv[dvb+F_+f] = mpv1; ypv[dvb+2*F_+f] = mpv2;
}

// ---------------- forward node MLP (full equivariant) ----------------
__global__ __launch_bounds__(256) void node_fwd_kernel(
    float* __restrict__ s, float* __restrict__ v, float* __restrict__ ps, float* __restrict__ pv,
    const float* __restrict__ ys, const float* __restrict__ yv,
    const float* __restrict__ yps, const float* __restrict__ ypv,
    const float* __restrict__ W1, const float* __restrict__ b1v,
    const float* __restrict__ W2, const float* __restrict__ b2v,
    float* __restrict__ a_s, float* __restrict__ a_v,
    float* __restrict__ a_ps, float* __restrict__ a_pv) {
  int gid = blockIdx.x * 256 + threadIdx.x;
  int n = gid >> 5, f = gid & 31;
  size_t ib = gid;
  size_t vb = (size_t)n*3*F_ + f;
  float y0s  = s[ib] + ys[ib];
  float y0v0 = v[vb] + yv[vb];
  float y0v1 = v[vb+F_] + yv[vb+F_];
  float y0v2 = v[vb+2*F_] + yv[vb+2*F_];
  float y0ps = ps[ib] + yps[ib];
  float y0pv0 = pv[vb] + ypv[vb];
  float y0pv1 = pv[vb+F_] + ypv[vb+F_];
  float y0pv2 = pv[vb+2*F_] + ypv[vb+2*F_];
  const float* W1s = W1; const float* W1v = W1 + F_*F_;
  const float* W1p = W1 + 2*F_*F_; const float* W1q = W1 + 3*F_*F_;
  float as_ = b1v[f], av0=0.f, av1=0.f, av2=0.f, aps_=0.f, apv0=0.f, apv1=0.f, apv2=0.f;
#pragma unroll
  for (int fp = 0; fp < F_; ++fp) {
    float w_s = W1s[fp*F_+f], w_v = W1v[fp*F_+f], w_p = W1p[fp*F_+f], w_q = W1q[fp*F_+f];
    as_  += __shfl(y0s, fp, 32)*w_s;
    av0  += __shfl(y0v0, fp, 32)*w_v;
    av1  += __shfl(y0v1, fp, 32)*w_v;
    av2  += __shfl(y0v2, fp, 32)*w_v;
    aps_ += __shfl(y0ps, fp, 32)*w_p;
    apv0 += __shfl(y0pv0, fp, 32)*w_q;
    apv1 += __shfl(y0pv1, fp, 32)*w_q;
    apv2 += __shfl(y0pv2, fp, 32)*w_q;
  }
  a_s[ib]=as_; a_v[vb]=av0; a_v[vb+F_]=av1; a_v[vb+2*F_]=av2;
  a_ps[ib]=aps_; a_pv[vb]=apv0; a_pv[vb+F_]=apv1; a_pv[vb+2*F_]=apv2;
  float g = sigm(as_);
  float hs=as_*g, hv0=av0*g, hv1=av1*g, hv2=av2*g, hps=aps_*g, hpv0=apv0*g, hpv1=apv1*g, hpv2=apv2*g;
  const float* W2s = W2; const float* W2v = W2 + F_*F_;
  const float* W2p = W2 + 2*F_*F_; const float* W2q = W2 + 3*F_*F_;
  float os_ = b2v[f], ov0=0.f, ov1=0.f, ov2=0.f, ops_=0.f, opv0=0.f, opv1=0.f, opv2=0.f;
#pragma unroll
  for (int fp = 0; fp < F_; ++fp) {
    float w_s = W2s[fp*F_+f], w_v = W2v[fp*F_+f], w_p = W2p[fp*F_+f], w_q = W2q[fp*F_+f];
    os_  += __shfl(hs, fp, 32)*w_s;
    ov0  += __shfl(hv0, fp, 32)*w_v;
    ov1  += __shfl(hv1, fp, 32)*w_v;
    ov2  += __shfl(hv2, fp, 32)*w_v;
    ops_ += __shfl(hps, fp, 32)*w_p;
    opv0 += __shfl(hpv0, fp, 32)*w_q;
    opv1 += __shfl(hpv1, fp, 32)*w_q;
    opv2 += __shfl(hpv2, fp, 32)*w_q;
  }
  s[ib] += os_;
  v[vb] += ov0; v[vb+F_] += ov1; v[vb+2*F_] += ov2;
  ps[ib] += ops_;
  pv[vb] += opv0; pv[vb+F_] += opv1; pv[vb+2*F_] += opv2;
}

// ---------------- forward last (scalar) pass: warp per dst node ----------------
__global__ __launch_bounds__(256) void edge_fwd_last_csr(
    const int* __restrict__ dst_off, const int* __restrict__ dst_perm,
    const int* __restrict__ src,
    const float* __restrict__ rad, const float* __restrict__ u3,
    const float* __restrict__ Wb0, const float* __restrict__ Wb1, const float* __restrict__ pwl,
    const float* __restrict__ s, const float* __restrict__ v, float* __restrict__ ys) {
  int gid = blockIdx.x * 256 + threadIdx.x;
  int n = gid >> 5, f = gid & 31;
  float wb0[K_], wb1[K_];
#pragma unroll
  for (int k = 0; k < K_; ++k) { wb0[k] = Wb0[k*F_+f]; wb1[k] = Wb1[k*F_+f]; }
  float p0 = pwl[f], p1 = pwl[F_+f];
  float m = 0.f;
  int j0 = dst_off[n], j1 = dst_off[n+1];
  for (int j = j0; j < j1; ++j) {
    int e = dst_perm[j];
    int ns = src[e];
    float radl = (f < K_) ? rad[(size_t)e*K_ + f] : 0.f;
    float q0 = 0.f, q1 = 0.f;
#pragma unroll
    for (int k = 0; k < K_; ++k) {
      float rk = __shfl(radl, k, 32);
      q0 += rk * wb0[k];
      q1 += rk * wb1[k];
    }
    float u0 = u3[(size_t)e*3+0], u1 = u3[(size_t)e*3+1], u2 = u3[(size_t)e*3+2];
    float se = s[(size_t)ns*F_+f];
    size_t vb = (size_t)ns*3*F_;
    float vu = v[vb+f]*u0 + v[vb+F_+f]*u1 + v[vb+2*F_+f]*u2;
    m += p0*se*q0 + p1*vu*q1;
  }
  ys[(size_t)n*F_+f] = m;
}

__global__ __launch_bounds__(256) void node_fwd_last_kernel(
    float* __restrict__ s, const float* __restrict__ ys,
    const float* __restrict__ W1, const float* __restrict__ b1v,
    const float* __restrict__ W2, const float* __restrict__ b2v,
    float* __restrict__ a_l, const float* __restrict__ w_out,
    const float* __restrict__ ebias, const int* __restrict__ Z,
    const int* __restrict__ bseg, float* __restrict__ energy) {
  __shared__ float bins[B_];
  int tid = threadIdx.x;
  if (tid < B_) bins[tid] = 0.f;
  __syncthreads();
  int gid = blockIdx.x * 256 + tid;
  int n = gid >> 5, f = gid & 31;
  float y0 = s[gid] + ys[gid];
  float a = b1v[f];
#pragma unroll
  for (int fp = 0; fp < F_; ++fp) a += __shfl(y0, fp, 32) * W1[fp*F_+f];
  a_l[gid] = a;
  float g = sigm(a);
  float h = a * g;
  float o = b2v[f];
#pragma unroll
  for (int fp = 0; fp < F_; ++fp) o += __shfl(h, fp, 32) * W2[fp*F_+f];
  float sn = s[gid] + o;
  s[gid] = sn;
  float c = sn * w_out[f];
#pragma unroll
  for (int off = 16; off > 0; off >>= 1) c += __shfl_xor(c, off, 32);
  if (f == 0) {
    c += ebias[Z[n]];
    atomicAdd(&bins[bseg[n]], c);
  }
  __syncthreads();
  if (tid < B_) atomicAdd(&energy[tid], bins[tid]);
}

// ---------------- backward last (scalar) pass ----------------
__global__ __launch_bounds__(256) void b1_last_kernel(
    float* __restrict__ s, const float* __restrict__ a_l,
    const float* __restrict__ W1, const float* __restrict__ W2, const float* __restrict__ b2v,
    float* __restrict__ Gs, float* __restrict__ ys) {
  int gid = blockIdx.x * 256 + threadIdx.x;
  int f = gid & 31;
  float a = a_l[gid];
  float g = sigm(a);
  float h = a * g;
  float o = b2v[f];
#pragma unroll
  for (int fp = 0; fp < F_; ++fp) o += __shfl(h, fp, 32) * W2[fp*F_+f];
  s[gid] -= o;                       // reconstruct s_4
  float gso = Gs[gid];
  float gh = 0.f;
#pragma unroll
  for (int fp = 0; fp < F_; ++fp) gh += __shfl(gso, fp, 32) * W2[f*F_+fp];
  float ga = gh * (g + a*g*(1.f - g));
  float gy = 0.f;
#pragma unroll
  for (int fp = 0; fp < F_; ++fp) gy += __shfl(ga, fp, 32) * W1[f*F_+fp];
  ys[gid] = gy;
  Gs[gid] = gso + gy;
}

// b2_last, dst side: grad_rad/grad_u (edge-owned, plain RMW)
__global__ __launch_bounds__(256) void b2_last_d_kernel(
    const int* __restrict__ dst_off, const int* __restrict__ dst_perm,
    const int* __restrict__ src,
    const float* __restrict__ rad, const float* __restrict__ u3,
    const float* __restrict__ Wb0, const float* __restrict__ Wb1, const float* __restrict__ pwl,
    const float* __restrict__ s, const float* __restrict__ v, const float* __restrict__ ysg,
    float* __restrict__ grad_rad, float* __restrict__ grad_u) {
  int gid = blockIdx.x * 256 + threadIdx.x;
  int n = gid >> 5, f = gid & 31;
  float wb0[K_], wb1[K_];
#pragma unroll
  for (int k = 0; k < K_; ++k) { wb0[k] = Wb0[k*F_+f]; wb1[k] = Wb1[k*F_+f]; }
  float p0 = pwl[f], p1 = pwl[F_+f];
  float gm = ysg[(size_t)n*F_+f];
  int j0 = dst_off[n], j1 = dst_off[n+1];
  for (int j = j0; j < j1; ++j) {
    int e = dst_perm[j];
    int ns = src[e];
    float radl = (f < K_) ? rad[(size_t)e*K_ + f] : 0.f;
    float q0 = 0.f, q1 = 0.f;
#pragma unroll
    for (int k = 0; k < K_; ++k) {
      float rk = __shfl(radl, k, 32);
      q0 += rk * wb0[k];
      q1 += rk * wb1[k];
    }
    float u0 = u3[(size_t)e*3+0], u1 = u3[(size_t)e*3+1], u2 = u3[(size_t)e*3+2];
    float se = s[(size_t)ns*F_+f];
    size_t vb = (size_t)ns*3*F_;
    float ve0 = v[vb+f], ve1 = v[vb+F_+f], ve2 = v[vb+2*F_+f];
    float vu = ve0*u0 + ve1*u1 + ve2*u2;
    float gq0 = p0*se*gm;
    float gq1 = p1*vu*gm;
    float keep = 0.f;
#pragma unroll
    for (int k = 0; k < K_; ++k) {
      float pr = gq0*wb0[k] + gq1*wb1[k];
#pragma unroll
      for (int off = 16; off > 0; off >>= 1) pr += __shfl_xor(pr, off, 32);
      if (f == k) keep = pr;
    }
    if (f < K_) grad_rad[(size_t)e*K_+f] += keep;
    float t1 = p1*q1*gm;
    float g0 = t1*ve0, g1 = t1*ve1, g2 = t1*ve2;
#pragma unroll
    for (int off = 16; off > 0; off >>= 1) {
      g0 += __shfl_xor(g0, off, 32);
      g1 += __shfl_xor(g1, off, 32);
      g2 += __shfl_xor(g2, off, 32);
    }
    if (f < 3) grad_u[(size_t)e*3+f] += (f==0 ? g0 : (f==1 ? g1 : g2));
  }
}

// b2_last, src side: G accumulation (warp per src node, no atomics)
__global__ __launch_bounds__(256) void b2_last_s_kernel(
    const int* __restrict__ src_off, const int* __restrict__ src_perm,
    const int* __restrict__ dst,
    const float* __restrict__ rad, const float* __restrict__ u3,
    const float* __restrict__ Wb0, const float* __restrict__ Wb1, const float* __restrict__ pwl,
    const float* __restrict__ ysg,
    float* __restrict__ Gs, float* __restrict__ Gv) {
  int gid = blockIdx.x * 256 + threadIdx.x;
  int n = gid >> 5, f = gid & 31;
  float wb0[K_], wb1[K_];
#pragma unroll
  for (int k = 0; k < K_; ++k) { wb0[k] = Wb0[k*F_+f]; wb1[k] = Wb1[k*F_+f]; }
  float p0 = pwl[f], p1 = pwl[F_+f];
  float ags = 0.f, agv0 = 0.f, agv1 = 0.f, agv2 = 0.f;
  int j0 = src_off[n], j1 = src_off[n+1];
  for (int j = j0; j < j1; ++j) {
    int e = src_perm[j];
    int nd = dst[e];
    float radl = (f < K_) ? rad[(size_t)e*K_ + f] : 0.f;
    float q0 = 0.f, q1 = 0.f;
#pragma unroll
    for (int k = 0; k < K_; ++k) {
      float rk = __shfl(radl, k, 32);
      q0 += rk * wb0[k];
      q1 += rk * wb1[k];
    }
    float u0 = u3[(size_t)e*3+0], u1 = u3[(size_t)e*3+1], u2 = u3[(size_t)e*3+2];
    float gm = ysg[(size_t)nd*F_+f];
    ags += p0*q0*gm;
    float t1 = p1*q1*gm;
    agv0 += t1*u0; agv1 += t1*u1; agv2 += t1*u2;
  }
  size_t sb = (size_t)n*F_, vb = (size_t)n*3*F_;
  Gs[sb+f] += ags;
  Gv[vb+f] += agv0; Gv[vb+F_+f] += agv1; Gv[vb+2*F_+f] += agv2;
}

// ---------------- backward node MLP (full equivariant) ----------------
__global__ __launch_bounds__(256) void b1_kernel(
    float* __restrict__ s, float* __restrict__ v, float* __restrict__ ps, float* __restrict__ pv,
    const float* __restrict__ a_s, const float* __restrict__ a_v,
    const float* __restrict__ a_ps, const float* __restrict__ a_pv,
    const float* __restrict__ W1, const float* __restrict__ W2, const float* __restrict__ b2v,
    float* __restrict__ Gs, float* __restrict__ Gv, float* __restrict__ Gps, float* __restrict__ Gpv,
    float* __restrict__ ys, float* __restrict__ yv, float* __restrict__ yps, float* __restrict__ ypv) {
  int gid = blockIdx.x * 256 + threadIdx.x;
  int n = gid >> 5, f = gid & 31;
  size_t ib = gid;
  size_t vb = (size_t)n*3*F_ + f;
  float as_ = a_s[ib], av0 = a_v[vb], av1 = a_v[vb+F_], av2 = a_v[vb+2*F_];
  float aps_ = a_ps[ib], apv0 = a_pv[vb], apv1 = a_pv[vb+F_], apv2 = a_pv[vb+2*F_];
  float g = sigm(as_);
  float gp = g * (1.f - g);
  float hs=as_*g, hv0=av0*g, hv1=av1*g, hv2=av2*g, hps=aps_*g, hpv0=apv0*g, hpv1=apv1*g, hpv2=apv2*g;
  const float* W2s = W2; const float* W2v = W2 + F_*F_;
  const float* W2p = W2 + 2*F_*F_; const float* W2q = W2 + 3*F_*F_;
  const float* W1s = W1; const float* W1v = W1 + F_*F_;
  const float* W1p = W1 + 2*F_*F_; const float* W1q = W1 + 3*F_*F_;
  float os_ = b2v[f], ov0=0.f, ov1=0.f, ov2=0.f, ops_=0.f, opv0=0.f, opv1=0.f, opv2=0.f;
#pragma unroll
  for (int fp = 0; fp < F_; ++fp) {
    float w_s = W2s[fp*F_+f], w_v = W2v[fp*F_+f], w_p = W2p[fp*F_+f], w_q = W2q[fp*F_+f];
    os_  += __shfl(hs, fp, 32)*w_s;
    ov0  += __shfl(hv0, fp, 32)*w_v;
    ov1  += __shfl(hv1, fp, 32)*w_v;
    ov2  += __shfl(hv2, fp, 32)*w_v;
    ops_ += __shfl(hps, fp, 32)*w_p;
    opv0 += __shfl(hpv0, fp, 32)*w_q;
    opv1 += __shfl(hpv1, fp, 32)*w_q;
    opv2 += __shfl(hpv2, fp, 32)*w_q;
  }
  s[ib] -= os_;
  v[vb] -= ov0; v[vb+F_] -= ov1; v[vb+2*F_] -= ov2;
  ps[ib] -= ops_;
  pv[vb] -= opv0; pv[vb+F_] -= opv1; pv[vb+2*F_] -= opv2;
  float GsV = Gs[ib], Gv0 = Gv[vb], Gv1 = Gv[vb+F_], Gv2 = Gv[vb+2*F_];
  float GpsV = Gps[ib], Gq0 = Gpv[vb], Gq1 = Gpv[vb+F_], Gq2 = Gpv[vb+2*F_];
  float ghs=0.f, ghv0=0.f, ghv1=0.f, ghv2=0.f, ghps=0.f, ghpv0=0.f, ghpv1=0.f, ghpv2=0.f;
#pragma unroll
  for (int fp = 0; fp < F_; ++fp) {
    float w_s = W2s[f*F_+fp], w_v = W2v[f*F_+fp], w_p = W2p[f*F_+fp], w_q = W2q[f*F_+fp];
    ghs   += __shfl(GsV, fp, 32)*w_s;
    ghv0  += __shfl(Gv0, fp, 32)*w_v;
    ghv1  += __shfl(Gv1, fp, 32)*w_v;
    ghv2  += __shfl(Gv2, fp, 32)*w_v;
    ghps  += __shfl(GpsV, fp, 32)*w_p;
    ghpv0 += __shfl(Gq0, fp, 32)*w_q;
    ghpv1 += __shfl(Gq1, fp, 32)*w_q;
    ghpv2 += __shfl(Gq2, fp, 32)*w_q;
  }
  float gas = ghs*g + (ghs*as_ + ghv0*av0 + ghv1*av1 + ghv2*av2 + ghps*aps_
                       + ghpv0*apv0 + ghpv1*apv1 + ghpv2*apv2) * gp;
  float gav0 = ghv0*g, gav1 = ghv1*g, gav2 = ghv2*g;
  float gaps = ghps*g;
  float gapv0 = ghpv0*g, gapv1 = ghpv1*g, gapv2 = ghpv2*g;
  float gys_=0.f, gyv0=0.f, gyv1=0.f, gyv2=0.f, gyps_=0.f, gypv0=0.f, gypv1=0.f, gypv2=0.f;
#pragma unroll
  for (int fp = 0; fp < F_; ++fp) {
    float w_s = W1s[f*F_+fp], w_v = W1v[f*F_+fp], w_p = W1p[f*F_+fp], w_q = W1q[f*F_+fp];
    gys_  += __shfl(gas, fp, 32)*w_s;
    gyv0  += __shfl(gav0, fp, 32)*w_v;
    gyv1  += __shfl(gav1, fp, 32)*w_v;
    gyv2  += __shfl(gav2, fp, 32)*w_v;
    gyps_ += __shfl(gaps, fp, 32)*w_p;
    gypv0 += __shfl(gapv0, fp, 32)*w_q;
    gypv1 += __shfl(gapv1, fp, 32)*w_q;
    gypv2 += __shfl(gapv2, fp, 32)*w_q;
  }
  ys[ib]=gys_; yv[vb]=gyv0; yv[vb+F_]=gyv1; yv[vb+2*F_]=gyv2;
  yps[ib]=gyps_; ypv[vb]=gypv0; ypv[vb+F_]=gypv1; ypv[vb+2*F_]=gypv2;
  Gs[ib]=GsV+gys_; Gv[vb]=Gv0+gyv0; Gv[vb+F_]=Gv1+gyv1; Gv[vb+2*F_]=Gv2+gyv2;
  Gps[ib]=GpsV+gyps_; Gpv[vb]=Gq0+gypv0; Gpv[vb+F_]=Gq1+gypv1; Gpv[vb+2*F_]=Gq2+gypv2;
}

// ---------------- backward edge pass, dst side: grad_rad / grad_u ----------------
__global__ __launch_bounds__(256) void b2d_kernel(
    const int* __restrict__ dst_off, const int* __restrict__ dst_perm,
    const int* __restrict__ src,
    const float* __restrict__ rad, const float* __restrict__ u3,
    const float* __restrict__ Wb0, const float* __restrict__ Wb1, const float* __restrict__ pw,
    const float* __restrict__ s, const float* __restrict__ v,
    const float* __restrict__ ps, const float* __restrict__ pv,
    const float* __restrict__ ys, const float* __restrict__ yv,
    const float* __restrict__ yps, const float* __restrict__ ypv,
    float* __restrict__ grad_rad, float* __restrict__ grad_u) {
  int gid = blockIdx.x * 256 + threadIdx.x;
  int n = gid >> 5, f = gid & 31;
  float wb0[K_], wb1[K_];
#pragma unroll
  for (int k = 0; k < K_; ++k) { wb0[k] = Wb0[k*F_+f]; wb1[k] = Wb1[k*F_+f]; }
  float pw0=pw[f],      pw1=pw[F_+f],   pw2=pw[2*F_+f], pw3=pw[3*F_+f], pw4=pw[4*F_+f];
  float pw5=pw[5*F_+f], pw6=pw[6*F_+f], pw7=pw[7*F_+f], pw8=pw[8*F_+f], pw9=pw[9*F_+f];
  size_t db = (size_t)n*F_, dvb = (size_t)n*3*F_;
  float gms = ys[db+f];
  float gmv0 = yv[dvb+f], gmv1 = yv[dvb+F_+f], gmv2 = yv[dvb+2*F_+f];
  float gmps = yps[db+f];
  float gmpv0 = ypv[dvb+f], gmpv1 = ypv[dvb+F_+f], gmpv2 = ypv[dvb+2*F_+f];
  int j0 = dst_off[n], j1 = dst_off[n+1];
  for (int j = j0; j < j1; ++j) {
    int e = dst_perm[j];
    int ns = src[e];
    float radl = (f < K_) ? rad[(size_t)e*K_ + f] : 0.f;
    float q1 = 0.f;
#pragma unroll
    for (int k = 0; k < K_; ++k) {
      float rk = __shfl(radl, k, 32);
      q1 += rk * wb1[k];
    }
    float u0 = u3[(size_t)e*3+0], u1 = u3[(size_t)e*3+1], u2 = u3[(size_t)e*3+2];
    size_t sb = (size_t)ns*F_, svb = (size_t)ns*3*F_;
    float se = s[sb+f], pse = ps[sb+f];
    float ve0 = v[svb+f], ve1 = v[svb+F_+f], ve2 = v[svb+2*F_+f];
    float pve0 = pv[svb+f], pve1 = pv[svb+F_+f], pve2 = pv[svb+2*F_+f];
    float udgmv  = u0*gmv0 + u1*gmv1 + u2*gmv2;
    float udgmpv = u0*gmpv0 + u1*gmpv1 + u2*gmpv2;
    float vu  = ve0*u0 + ve1*u1 + ve2*u2;
    float pvu = pve0*u0 + pve1*u1 + pve2*u2;
    float cpu0 = pve1*u2 - pve2*u1, cpu1 = pve2*u0 - pve0*u2, cpu2 = pve0*u1 - pve1*u0;
    float cvu0 = ve1*u2 - ve2*u1,  cvu1 = ve2*u0 - ve0*u2,  cvu2 = ve0*u1 - ve1*u0;
    float gq0 = pw0*se*gms + pw2*pse*gmps
              + pw4*(ve0*gmv0 + ve1*gmv1 + ve2*gmv2)
              + pw7*(pve0*gmpv0 + pve1*gmpv1 + pve2*gmpv2);
    float gq1 = pw1*vu*gms + pw3*pvu*gmps + pw5*se*udgmv
              + pw6*(cpu0*gmv0 + cpu1*gmv1 + cpu2*gmv2)
              + pw8*pse*udgmpv
              + pw9*(cvu0*gmpv0 + cvu1*gmpv1 + cvu2*gmpv2);
    float gmvxpve0 = gmv1*pve2 - gmv2*pve1, gmvxpve1 = gmv2*pve0 - gmv0*pve2, gmvxpve2 = gmv0*pve1 - gmv1*pve0;
    float gmpvxve0 = gmpv1*ve2 - gmpv2*ve1, gmpvxve1 = gmpv2*ve0 - gmpv0*ve2, gmpvxve2 = gmpv0*ve1 - gmpv1*ve0;
    float gu0 = q1*(pw1*gms*ve0 + pw3*gmps*pve0 + pw5*se*gmv0 + pw6*gmvxpve0 + pw8*pse*gmpv0 + pw9*gmpvxve0);
    float gu1 = q1*(pw1*gms*ve1 + pw3*gmps*pve1 + pw5*se*gmv1 + pw6*gmvxpve1 + pw8*pse*gmpv1 + pw9*gmpvxve1);
    float gu2 = q1*(pw1*gms*ve2 + pw3*gmps*pve2 + pw5*se*gmv2 + pw6*gmvxpve2 + pw8*pse*gmpv2 + pw9*gmpvxve2);
    float keep = 0.f;
#pragma unroll
    for (int k = 0; k < K_; ++k) {
      float pr = gq0*wb0[k] + gq1*wb1[k];
#pragma unroll
      for (int off = 16; off > 0; off >>= 1) pr += __shfl_xor(pr, off, 32);
      if (f == k) keep = pr;
    }
    if (f < K_) grad_rad[(size_t)e*K_+f] += keep;
#pragma unroll
    for (int off = 16; off > 0; off >>= 1) {
      gu0 += __shfl_xor(gu0, off, 32);
      gu1 += __shfl_xor(gu1, off, 32);
      gu2 += __shfl_xor(gu2, off, 32);
    }
    if (f < 3) grad_u[(size_t)e*3+f] += (f==0 ? gu0 : (f==1 ? gu1 : gu2));
  }
}

// ---------------- backward edge pass, src side: G accumulation ----------------
__global__ __launch_bounds__(256) void b2s_kernel(
    const int* __restrict__ src_off, const int* __restrict__ src_perm,
    const int* __restrict__ dst,
    const float* __restrict__ rad, const float* __restrict__ u3,
    const float* __restrict__ Wb0, const float* __restrict__ Wb1, const float* __restrict__ pw,
    const float* __restrict__ ys, const float* __restrict__ yv,
    const float* __restrict__ yps, const float* __restrict__ ypv,
    float* __restrict__ Gs, float* __restrict__ Gv,
    float* __restrict__ Gps, float* __restrict__ Gpv) {
  int gid = blockIdx.x * 256 + threadIdx.x;
  int n = gid >> 5, f = gid & 31;
  float wb0[K_], wb1[K_];
#pragma unroll
  for (int k = 0; k < K_; ++k) { wb0[k] = Wb0[k*F_+f]; wb1[k] = Wb1[k*F_+f]; }
  float pw0=pw[f],      pw1=pw[F_+f],   pw2=pw[2*F_+f], pw3=pw[3*F_+f], pw4=pw[4*F_+f];
  float pw5=pw[5*F_+f], pw6=pw[6*F_+f], pw7=pw[7*F_+f], pw8=pw[8*F_+f], pw9=pw[9*F_+f];
  float ase=0.f, apse=0.f;
  float ave0=0.f, ave1=0.f, ave2=0.f, apve0=0.f, apve1=0.f, apve2=0.f;
  int j0 = src_off[n], j1 = src_off[n+1];
  for (int j = j0; j < j1; ++j) {
    int e = src_perm[j];
    int nd = dst[e];
    float radl = (f < K_) ? rad[(size_t)e*K_ + f] : 0.f;
    float q0 = 0.f, q1 = 0.f;
#pragma unroll
    for (int k = 0; k < K_; ++k) {
      float rk = __shfl(radl, k, 32);
      q0 += rk * wb0[k];
      q1 += rk * wb1[k];
    }
    float u0 = u3[(size_t)e*3+0], u1 = u3[(size_t)e*3+1], u2 = u3[(size_t)e*3+2];
    size_t db = (size_t)nd*F_, dvb = (size_t)nd*3*F_;
    float gms = ys[db+f];
    float gmv0 = yv[dvb+f], gmv1 = yv[dvb+F_+f], gmv2 = yv[dvb+2*F_+f];
    float gmps = yps[db+f];
    float gmpv0 = ypv[dvb+f], gmpv1 = ypv[dvb+F_+f], gmpv2 = ypv[dvb+2*F_+f];
    float udgmv  = u0*gmv0 + u1*gmv1 + u2*gmv2;
    float udgmpv = u0*gmpv0 + u1*gmpv1 + u2*gmpv2;
    float uxgmpv0 = u1*gmpv2 - u2*gmpv1, uxgmpv1 = u2*gmpv0 - u0*gmpv2, uxgmpv2 = u0*gmpv1 - u1*gmpv0;
    float uxgmv0  = u1*gmv2 - u2*gmv1,   uxgmv1  = u2*gmv0 - u0*gmv2,   uxgmv2  = u0*gmv1 - u1*gmv0;
    ase  += pw0*q0*gms  + pw5*q1*udgmv;
    apse += pw2*q0*gmps + pw8*q1*udgmpv;
    ave0 += pw1*u0*q1*gms + pw4*q0*gmv0 + pw9*q1*uxgmpv0;
    ave1 += pw1*u1*q1*gms + pw4*q0*gmv1 + pw9*q1*uxgmpv1;
    ave2 += pw1*u2*q1*gms + pw4*q0*gmv2 + pw9*q1*uxgmpv2;
    apve0 += pw3*u0*q1*gmps + pw7*q0*gmpv0 + pw6*q1*uxgmv0;
    apve1 += pw3*u1*q1*gmps + pw7*q0*gmpv1 + pw6*q1*uxgmv1;
    apve2 += pw3*u2*q1*gmps + pw7*q0*gmpv2 + pw6*q1*uxgmv2;
  }
  size_t sb = (size_t)n*F_, svb = (size_t)n*3*F_;
  Gs[sb+f]  += ase;
  Gps[sb+f] += apse;
  Gv[svb+f] += ave0;  Gv[svb+F_+f] += ave1;  Gv[svb+2*F_+f] += ave2;
  Gpv[svb+f] += apve0; Gpv[svb+F_+f] += apve1; Gpv[svb+2*F_+f] += apve2;
}

// ---------------- basis backward: (grad_rad, grad_u) -> forces ----------------
__global__ void basis_bwd_kernel(const int* __restrict__ dst, const int* __restrict__ src,
                                 const float* __restrict__ rr, const float* __restrict__ u3,
                                 const float* __restrict__ grad_rad, const float* __restrict__ grad_u,
                                 float* __restrict__ forces) {
  int e = blockIdx.x * blockDim.x + threadIdx.x;
  if (e >= E_) return;
  float r = rr[e];
  float u0 = u3[(size_t)e*3+0], u1 = u3[(size_t)e*3+1], u2 = u3[(size_t)e*3+2];
  float t = r / (1.f + r);
  float b = 1.f - t;
  float tp[K_], bp[K_];
  tp[0] = 1.f; bp[0] = 1.f;
#pragma unroll
  for (int k = 1; k < K_; ++k) { tp[k] = tp[k-1]*t; bp[k] = bp[k-1]*b; }
  float cut = 0.f, dcut = 0.f;
  if (r < CUT_) {
    float den = (CUT_ - r) * (CUT_ + r);
    cut = expf(-r*r/den);
    dcut = (cut > 0.f) ? cut * (-2.f*r*CUT_*CUT_/(den*den)) : 0.f;
  }
  float inv1pr = 1.f / (1.f + r);
  float dtdr = inv1pr * inv1pr;
  float gr = 0.f;
#pragma unroll
  for (int k = 0; k < K_; ++k) {
    float rrk = c_binom[k]*tp[k]*bp[K_-1-k];
    float d1 = (k > 0) ? k*tp[k-1]*bp[K_-1-k] : 0.f;
    float d2 = (k < K_-1) ? (K_-1-k)*tp[k]*bp[K_-2-k] : 0.f;
    float drdt = c_binom[k]*(d1 - d2);
    gr += grad_rad[(size_t)e*K_+k] * (drdt*dtdr*cut + rrk*dcut);
  }
  float g0 = grad_u[(size_t)e*3+0], g1 = grad_u[(size_t)e*3+1], g2 = grad_u[(size_t)e*3+2];
  float gdu = g0*u0 + g1*u1 + g2*u2;
  float invr = 1.f / r;
  float gd0 = gr*u0 + (g0 - gdu*u0)*invr;
  float gd1 = gr*u1 + (g1 - gdu*u1)*invr;
  float gd2 = gr*u2 + (g2 - gdu*u2)*invr;
  int ns = src[e], nd = dst[e];
  atomicAdd(&forces[(size_t)ns*3+0], gd0);
  atomicAdd(&forces[(size_t)ns*3+1], gd1);
  atomicAdd(&forces[(size_t)ns*3+2], gd2);
  atomicAdd(&forces[(size_t)nd*3+0], -gd0);
  atomicAdd(&forces[(size_t)nd*3+1], -gd1);
  atomicAdd(&forces[(size_t)nd*3+2], -gd2);
}

// ---------------- host launcher ----------------
extern "C" void kernel_launch(void* const* d_in, const int* in_sizes, int n_in,
                              void* d_out, int out_size, void* d_ws, size_t ws_size,
                              hipStream_t stream) {
  const int*   Z     = (const int*)d_in[0];
  const float* pos   = (const float*)d_in[1];
  const int*   dst   = (const int*)d_in[2];
  const int*   src   = (const int*)d_in[3];
  const int*   bseg  = (const int*)d_in[4];
  const float* embed = (const float*)d_in[6];
  const float* Wb0   = (const float*)d_in[7];
  const float* Wb1   = (const float*)d_in[8];
  const float* pw    = (const float*)d_in[9];
  const float* Wd1   = (const float*)d_in[10];
  const float* bd1   = (const float*)d_in[11];
  const float* Wd2   = (const float*)d_in[12];
  const float* bd2   = (const float*)d_in[13];
  const float* Wb0l  = (const float*)d_in[14];
  const float* Wb1l  = (const float*)d_in[15];
  const float* pwl   = (const float*)d_in[16];
  const float* Wd1l  = (const float*)d_in[17];
  const float* bd1l  = (const float*)d_in[18];
  const float* Wd2l  = (const float*)d_in[19];
  const float* bd2l  = (const float*)d_in[20];
  const float* w_out = (const float*)d_in[21];
  const float* ebias = (const float*)d_in[22];

  float* out = (float*)d_out;
  float* energy = out;          // (B,)
  float* forces = out + B_;     // (N,3)

  float* ws = nullptr;
  (void)hipGetSymbolAddress((void**)&ws, HIP_SYMBOL(g_ws));

  const size_t NF = (size_t)N_ * F_;
  const size_t NV = (size_t)N_ * 3 * F_;
  float* rad      = ws;                       // E*K
  float* u3       = rad + (size_t)E_*K_;      // E*3
  float* rr       = u3 + (size_t)E_*3;        // E
  float* s        = rr + E_;                  // N*F
  float* v        = s + NF;                   // N*3F
  float* ps       = v + NV;                   // N*F
  float* pv       = ps + NF;                  // N*3F
  float* ys       = pv + NV;                  // N*F
  float* yv       = ys + NF;                  // N*3F
  float* yps      = yv + NV;                  // N*F
  float* ypv      = yps + NF;                 // N*3F
  float* Gs       = ypv + NV;                 // N*F
  float* Gv       = Gs + NF;                  // N*3F
  float* Gps      = Gv + NV;                  // N*F
  float* Gpv      = Gps + NF;                 // N*3F
  float* grad_rad = Gpv + NV;                 // E*K
  float* grad_u   = grad_rad + (size_t)E_*K_; // E*3
  float* a_s      = grad_u + (size_t)E_*3;    // 4*N*F
  float* a_v      = a_s + 4*NF;               // 4*N*3F
  float* a_ps     = a_v + 4*NV;               // 4*N*F
  float* a_pv     = a_ps + 4*NF;              // 4*N*3F
  float* a_l      = a_pv + 4*NV;              // N*F
  // int region (CSR)
  int* iws        = (int*)(a_l + NF);         // base: 106,800,000 floats
  int* cntd       = iws;                      // N
  int* cnts       = cntd + N_;                // N
  int* dst_off    = cnts + N_;                // N+1
  int* src_off    = dst_off + (N_+1);         // N+1
  int* dst_perm   = src_off + (N_+1);         // E
  int* src_perm   = dst_perm + E_;            // E
  int* curd       = src_perm + E_;            // N
  int* curs       = curd + N_;                // N

  const int TB = 256;
  const int nodeBlocks = (int)(NF / TB);             // 6250
  const int eThreadBlocks = (E_ + TB - 1) / TB;      // 1563
  const int nThreadBlocks = (N_ + TB - 1) / TB;      // 196

  // ---- CSR build ----
  fill_int_kernel<<<256, TB, 0, stream>>>(cntd, (size_t)2*N_, 0);
  hist_kernel<<<eThreadBlocks, TB, 0, stream>>>(dst, src, cntd, cnts);
  scan_kernel<<<2, 1024, 0, stream>>>(cntd, cnts, dst_off, src_off);
  cursor_init_kernel<<<nThreadBlocks, TB, 0, stream>>>(dst_off, src_off, curd, curs);
  scatter_kernel<<<eThreadBlocks, TB, 0, stream>>>(dst, src, curd, curs, dst_perm, src_perm);

  // ---- init state + geometry ----
  fill_kernel<<<2048, TB, 0, stream>>>(v, 7*NF, 0.f);  // v,ps,pv = 0
  init_embed_kernel<<<nodeBlocks, TB, 0, stream>>>(s, embed, Z);
  geom_kernel<<<eThreadBlocks, TB, 0, stream>>>(pos, dst, src, rad, u3, rr);

  // ---- 4 full equivariant passes ----
  for (int i = 0; i < 4; ++i) {
    edge_fwd_csr<<<nodeBlocks, TB, 0, stream>>>(
        dst_off, dst_perm, src, rad, u3,
        Wb0 + (size_t)i*K_*F_, Wb1 + (size_t)i*K_*F_, pw + (size_t)i*10*F_,
        s, v, ps, pv, ys, yv, yps, ypv);
    node_fwd_kernel<<<nodeBlocks, TB, 0, stream>>>(
        s, v, ps, pv, ys, yv, yps, ypv,
        Wd1 + (size_t)i*4*F_*F_, bd1 + (size_t)i*F_,
        Wd2 + (size_t)i*4*F_*F_, bd2 + (size_t)i*F_,
        a_s + i*NF, a_v + i*NV, a_ps + i*NF, a_pv + i*NV);
  }

  // ---- last scalar pass ----
  fill_kernel<<<592, TB, 0, stream>>>(out, (size_t)(B_ + N_*3), 0.f);
  edge_fwd_last_csr<<<nodeBlocks, TB, 0, stream>>>(
      dst_off, dst_perm, src, rad, u3, Wb0l, Wb1l, pwl, s, v, ys);
  node_fwd_last_kernel<<<nodeBlocks, TB, 0, stream>>>(
      s, ys, Wd1l, bd1l, Wd2l, bd2l, a_l, w_out, ebias, Z, bseg, energy);

  // ---- backward init ----
  init_gs_kernel<<<nodeBlocks, TB, 0, stream>>>(Gs, w_out);
  fill_kernel<<<2048, TB, 0, stream>>>(Gv, 7*NF, 0.f);
  fill_kernel<<<2048, TB, 0, stream>>>(grad_rad, (size_t)E_*(K_+3), 0.f);

  // ---- last pass backward ----
  b1_last_kernel<<<nodeBlocks, TB, 0, stream>>>(s, a_l, Wd1l, Wd2l, bd2l, Gs, ys);
  b2_last_d_kernel<<<nodeBlocks, TB, 0, stream>>>(
      dst_off, dst_perm, src, rad, u3, Wb0l, Wb1l, pwl, s, v, ys, grad_rad, grad_u);
  b2_last_s_kernel<<<nodeBlocks, TB, 0, stream>>>(
      src_off, src_perm, dst, rad, u3, Wb0l, Wb1l, pwl, ys, Gs, Gv);

  // ---- 4 full passes backward ----
  for (int i = 3; i >= 0; --i) {
    b1_kernel<<<nodeBlocks, TB, 0, stream>>>(
        s, v, ps, pv,
        a_s + i*NF, a_v + i*NV, a_ps + i*NF, a_pv + i*NV,
        Wd1 + (size_t)i*4*F_*F_, Wd2 + (size_t)i*4*F_*F_, bd2 + (size_t)i*F_,
        Gs, Gv, Gps, Gpv, ys, yv, yps, ypv);
    b2d_kernel<<<nodeBlocks, TB, 0, stream>>>(
        dst_off, dst_perm, src, rad, u3,
        Wb0 + (size_t)i*K_*F_, Wb1 + (size_t)i*K_*F_, pw + (size_t)i*10*F_,
        s, v, ps, pv, ys, yv, yps, ypv, grad_rad, grad_u);
    b2s_kernel<<<nodeBlocks, TB, 0, stream>>>(
        src_off, src_perm, dst, rad, u3,
        Wb0 + (size_t)i*K_*F_, Wb1 + (size_t)i*K_*F_, pw + (size_t)i*10*F_,
        ys, yv, yps, ypv, Gs, Gv, Gps, Gpv);
  }

  // ---- basis backward -> forces ----
  basis_bwd_kernel<<<eThreadBlocks, TB, 0, stream>>>(
      dst, src, rr, u3, grad_rad, grad_u, forces);
}

// Round 6
// 4135.232 us; speedup vs baseline: 1.5200x; 1.2170x over previous
//
#include <hip/hip_runtime.h>
#include <math.h>

namespace {
constexpr int N_ = 50000;
constexpr int E_ = 400000;
constexpr int F_ = 32;
constexpr int K_ = 16;
constexpr int B_ = 10;
constexpr float CUT_ = 10.0f;
constexpr float EPS_ = 1e-8f;
constexpr size_t WS_FLOATS = 108500000;  // 107.2M floats + 1.2M ints + slack
}

// Static device scratch (d_ws size unknown). ~434 MB BSS.
__device__ float g_ws[WS_FLOATS];

__constant__ float c_binom[K_] = {1.f,15.f,105.f,455.f,1365.f,3003.f,5005.f,6435.f,
                                  6435.f,5005.f,3003.f,1365.f,455.f,105.f,15.f,1.f};

__device__ __forceinline__ float sigm(float x) { return 1.f / (1.f + expf(-x)); }

// ---------------- utility fills ----------------
__global__ void fill_kernel(float* __restrict__ p, size_t n, float v) {
  size_t i = (size_t)blockIdx.x * blockDim.x + threadIdx.x;
  size_t st = (size_t)gridDim.x * blockDim.x;
  for (; i < n; i += st) p[i] = v;
}

__global__ void fill_int_kernel(int* __restrict__ p, size_t n, int v) {
  size_t i = (size_t)blockIdx.x * blockDim.x + threadIdx.x;
  size_t st = (size_t)gridDim.x * blockDim.x;
  for (; i < n; i += st) p[i] = v;
}

__global__ void init_embed_kernel(float* __restrict__ s, const float* __restrict__ embed,
                                  const int* __restrict__ Z) {
  int gid = blockIdx.x * blockDim.x + threadIdx.x;
  int n = gid >> 5, f = gid & 31;
  s[gid] = embed[Z[n] * F_ + f];
}

__global__ void init_gs_kernel(float* __restrict__ Gs, const float* __restrict__ w_out) {
  int gid = blockIdx.x * blockDim.x + threadIdx.x;
  Gs[gid] = -w_out[gid & 31];
}

// ---------------- CSR build ----------------
__global__ void hist_kernel(const int* __restrict__ dst, const int* __restrict__ src,
                            int* __restrict__ cntd, int* __restrict__ cnts) {
  int e = blockIdx.x * blockDim.x + threadIdx.x;
  if (e < E_) { atomicAdd(&cntd[dst[e]], 1); atomicAdd(&cnts[src[e]], 1); }
}

__global__ __launch_bounds__(1024) void scan_kernel(
    const int* __restrict__ cntd, const int* __restrict__ cnts,
    int* __restrict__ offd, int* __restrict__ offs) {
  const int* cnt = blockIdx.x ? cnts : cntd;
  int* off = blockIdx.x ? offs : offd;
  __shared__ int part[1024];
  int tid = threadIdx.x;
  const int CH = (N_ + 1023) / 1024;  // 49
  int base = tid * CH;
  int sum = 0;
  for (int i = 0; i < CH; ++i) { int j = base + i; if (j < N_) sum += cnt[j]; }
  part[tid] = sum; __syncthreads();
  for (int d = 1; d < 1024; d <<= 1) {
    int t = (tid >= d) ? part[tid - d] : 0; __syncthreads();
    part[tid] += t; __syncthreads();
  }
  int run = (tid == 0) ? 0 : part[tid - 1];
  for (int i = 0; i < CH; ++i) {
    int j = base + i;
    if (j <= N_) { off[j] = run; if (j < N_) run += cnt[j]; }
  }
}

__global__ void cursor_init_kernel(const int* __restrict__ offd, const int* __restrict__ offs,
                                   int* __restrict__ curd, int* __restrict__ curs) {
  int i = blockIdx.x * blockDim.x + threadIdx.x;
  if (i < N_) { curd[i] = offd[i]; curs[i] = offs[i]; }
}

__global__ void scatter_kernel(const int* __restrict__ dst, const int* __restrict__ src,
                               int* __restrict__ curd, int* __restrict__ curs,
                               int* __restrict__ permd, int* __restrict__ perms) {
  int e = blockIdx.x * blockDim.x + threadIdx.x;
  if (e < E_) {
    permd[atomicAdd(&curd[dst[e]], 1)] = e;
    perms[atomicAdd(&curs[src[e]], 1)] = e;
  }
}

// ---------------- degree sort (descending) ----------------
__global__ void sort_hist_kernel(const int* __restrict__ offd, const int* __restrict__ offs,
                                 int* __restrict__ binc) {
  int n = blockIdx.x * blockDim.x + threadIdx.x;
  if (n < N_) {
    int dd = offd[n+1] - offd[n]; int bd = 63 - min(dd, 63);
    atomicAdd(&binc[bd], 1);
    int ds = offs[n+1] - offs[n]; int bs = 63 - min(ds, 63);
    atomicAdd(&binc[64 + bs], 1);
  }
}

__global__ void sort_scan_kernel(const int* __restrict__ binc, int* __restrict__ bcur) {
  int t = threadIdx.x;  // 0: dst side, 1: src side
  if (t < 2) {
    int base = t * 64;
    int run = 0;
    for (int i = 0; i < 64; ++i) { bcur[base + i] = run; run += binc[base + i]; }
  }
}

__global__ void sort_scatter_kernel(const int* __restrict__ offd, const int* __restrict__ offs,
                                    int* __restrict__ bcur,
                                    int* __restrict__ ord_d, int* __restrict__ ord_s) {
  int n = blockIdx.x * blockDim.x + threadIdx.x;
  if (n < N_) {
    int bd = 63 - min(offd[n+1] - offd[n], 63);
    ord_d[atomicAdd(&bcur[bd], 1)] = n;
    int bs = 63 - min(offs[n+1] - offs[n], 63);
    ord_s[atomicAdd(&bcur[64 + bs], 1)] = n;
  }
}

// ---------------- geometry / basis (rad + drad interleaved: rd[e][32]) ----------------
__global__ void geom_kernel(const float* __restrict__ pos, const int* __restrict__ dst,
                            const int* __restrict__ src, float* __restrict__ rd,
                            float* __restrict__ u3, float* __restrict__ rr) {
  int e = blockIdx.x * blockDim.x + threadIdx.x;
  if (e >= E_) return;
  int nd = dst[e], ns = src[e];
  float dx = pos[ns*3+0] - pos[nd*3+0];
  float dy = pos[ns*3+1] - pos[nd*3+1];
  float dz = pos[ns*3+2] - pos[nd*3+2];
  float r = sqrtf(dx*dx + dy*dy + dz*dz + EPS_);
  float t = r / (1.f + r);
  float b = 1.f - t;
  float tp[K_], bp[K_];
  tp[0] = 1.f; bp[0] = 1.f;
#pragma unroll
  for (int k = 1; k < K_; ++k) { tp[k] = tp[k-1]*t; bp[k] = bp[k-1]*b; }
  float cut = 0.f, dcut = 0.f;
  if (r < CUT_) {
    float den = (CUT_ - r) * (CUT_ + r);
    cut = expf(-r*r/den);
    dcut = cut * (-2.f*r*CUT_*CUT_/(den*den));
  }
  float inv1pr = 1.f / (1.f + r);
  float dtdr = inv1pr * inv1pr;
#pragma unroll
  for (int k = 0; k < K_; ++k) {
    float rrk = c_binom[k]*tp[k]*bp[K_-1-k];
    float d1 = (k > 0) ? k*tp[k-1]*bp[K_-1-k] : 0.f;
    float d2 = (k < K_-1) ? (K_-1-k)*tp[k]*bp[K_-2-k] : 0.f;
    float drdt = c_binom[k]*(d1 - d2);
    rd[(size_t)e*32 + k]      = rrk*cut;                     // rad_k
    rd[(size_t)e*32 + 16 + k] = drdt*dtdr*cut + rrk*dcut;    // d(rad_k)/dr
  }
  float invr = 1.f / r;
  u3[(size_t)e*3+0] = dx*invr;
  u3[(size_t)e*3+1] = dy*invr;
  u3[(size_t)e*3+2] = dz*invr;
  rr[e] = r;
}

// ---------------- forward edge pass: warp(32) per dst node, 64-thr blocks ----------------
__global__ __launch_bounds__(64) void edge_fwd_csr(
    const int* __restrict__ ord_d,
    const int* __restrict__ dst_off, const int* __restrict__ dst_perm,
    const int* __restrict__ src,
    const float* __restrict__ rd, const float* __restrict__ u3,
    const float* __restrict__ Wb0, const float* __restrict__ Wb1, const float* __restrict__ pw,
    const float* __restrict__ s, const float* __restrict__ v,
    const float* __restrict__ ps, const float* __restrict__ pv,
    float* __restrict__ ys, float* __restrict__ yv,
    float* __restrict__ yps, float* __restrict__ ypv) {
  int gid = blockIdx.x * 64 + threadIdx.x;
  int n = ord_d[gid >> 5];
  int f = gid & 31;
  float wb0[K_], wb1[K_];
#pragma unroll
  for (int k = 0; k < K_; ++k) { wb0[k] = Wb0[k*F_+f]; wb1[k] = Wb1[k*F_+f]; }
  float pw0=pw[f],      pw1=pw[F_+f],   pw2=pw[2*F_+f], pw3=pw[3*F_+f], pw4=pw[4*F_+f];
  float pw5=pw[5*F_+f], pw6=pw[6*F_+f], pw7=pw[7*F_+f], pw8=pw[8*F_+f], pw9=pw[9*F_+f];
  float ms=0.f, mps=0.f, mv0=0.f, mv1=0.f, mv2=0.f, mpv0=0.f, mpv1=0.f, mpv2=0.f;
  int j0 = dst_off[n], j1 = dst_off[n+1];
  for (int j = j0; j < j1; ++j) {
    int e = dst_perm[j];
    int ns = src[e];
    float radl = (f < K_) ? rd[(size_t)e*32 + f] : 0.f;
    float q0 = 0.f, q1 = 0.f;
#pragma unroll
    for (int k = 0; k < K_; ++k) {
      float rk = __shfl(radl, k, 32);
      q0 += rk * wb0[k];
      q1 += rk * wb1[k];
    }
    float u0 = u3[(size_t)e*3+0], u1 = u3[(size_t)e*3+1], u2 = u3[(size_t)e*3+2];
    size_t sb = (size_t)ns*F_, vb = (size_t)ns*3*F_;
    float se = s[sb+f], pse = ps[sb+f];
    float ve0 = v[vb+f], ve1 = v[vb+F_+f], ve2 = v[vb+2*F_+f];
    float pve0 = pv[vb+f], pve1 = pv[vb+F_+f], pve2 = pv[vb+2*F_+f];
    float vu  = ve0*u0 + ve1*u1 + ve2*u2;
    float pvu = pve0*u0 + pve1*u1 + pve2*u2;
    float cpu0 = pve1*u2 - pve2*u1, cpu1 = pve2*u0 - pve0*u2, cpu2 = pve0*u1 - pve1*u0;
    float cvu0 = ve1*u2 - ve2*u1,  cvu1 = ve2*u0 - ve0*u2,  cvu2 = ve0*u1 - ve1*u0;
    ms  += pw0*se*q0  + pw1*vu*q1;
    mps += pw2*pse*q0 + pw3*pvu*q1;
    mv0 += pw4*ve0*q0 + (pw5*se*u0 + pw6*cpu0)*q1;
    mv1 += pw4*ve1*q0 + (pw5*se*u1 + pw6*cpu1)*q1;
    mv2 += pw4*ve2*q0 + (pw5*se*u2 + pw6*cpu2)*q1;
    mpv0 += pw7*pve0*q0 + (pw8*pse*u0 + pw9*cvu0)*q1;
    mpv1 += pw7*pve1*q0 + (pw8*pse*u1 + pw9*cvu1)*q1;
    mpv2 += pw7*pve2*q0 + (pw8*pse*u2 + pw9*cvu2)*q1;
  }
  size_t db = (size_t)n*F_, dvb = (size_t)n*3*F_;
  ys[db+f] = ms;
  yps[db+f] = mps;
  yv[dvb+f] = mv0;   yv[dvb+F_+f] = mv1;   yv[dvb+2*F_+f] = mv2;
  ypv[dvb+f] = mpv0; ypv[dvb+F_+f] = mpv1; ypv[dvb+2*F_+f] = mpv2;
}

// ---------------- forward node MLP (full equivariant) ----------------
__global__ __launch_bounds__(256) void node_fwd_kernel(
    float* __restrict__ s, float* __restrict__ v, float* __restrict__ ps, float* __restrict__ pv,
    const float* __restrict__ ys, const float* __restrict__ yv,
    const float* __restrict__ yps, const float* __restrict__ ypv,
    const float* __restrict__ W1, const float* __restrict__ b1v,
    const float* __restrict__ W2, const float* __restrict__ b2v,
    float* __restrict__ a_s, float* __restrict__ a_v,
    float* __restrict__ a_ps, float* __restrict__ a_pv) {
  int gid = blockIdx.x * 256 + threadIdx.x;
  int n = gid >> 5, f = gid & 31;
  size_t ib = gid;
  size_t vb = (size_t)n*3*F_ + f;
  float y0s  = s[ib] + ys[ib];
  float y0v0 = v[vb] + yv[vb];
  float y0v1 = v[vb+F_] + yv[vb+F_];
  float y0v2 = v[vb+2*F_] + yv[vb+2*F_];
  float y0ps = ps[ib] + yps[ib];
  float y0pv0 = pv[vb] + ypv[vb];
  float y0pv1 = pv[vb+F_] + ypv[vb+F_];
  float y0pv2 = pv[vb+2*F_] + ypv[vb+2*F_];
  const float* W1s = W1; const float* W1v = W1 + F_*F_;
  const float* W1p = W1 + 2*F_*F_; const float* W1q = W1 + 3*F_*F_;
  float as_ = b1v[f], av0=0.f, av1=0.f, av2=0.f, aps_=0.f, apv0=0.f, apv1=0.f, apv2=0.f;
#pragma unroll
  for (int fp = 0; fp < F_; ++fp) {
    float w_s = W1s[fp*F_+f], w_v = W1v[fp*F_+f], w_p = W1p[fp*F_+f], w_q = W1q[fp*F_+f];
    as_  += __shfl(y0s, fp, 32)*w_s;
    av0  += __shfl(y0v0, fp, 32)*w_v;
    av1  += __shfl(y0v1, fp, 32)*w_v;
    av2  += __shfl(y0v2, fp, 32)*w_v;
    aps_ += __shfl(y0ps, fp, 32)*w_p;
    apv0 += __shfl(y0pv0, fp, 32)*w_q;
    apv1 += __shfl(y0pv1, fp, 32)*w_q;
    apv2 += __shfl(y0pv2, fp, 32)*w_q;
  }
  a_s[ib]=as_; a_v[vb]=av0; a_v[vb+F_]=av1; a_v[vb+2*F_]=av2;
  a_ps[ib]=aps_; a_pv[vb]=apv0; a_pv[vb+F_]=apv1; a_pv[vb+2*F_]=apv2;
  float g = sigm(as_);
  float hs=as_*g, hv0=av0*g, hv1=av1*g, hv2=av2*g, hps=aps_*g, hpv0=apv0*g, hpv1=apv1*g, hpv2=apv2*g;
  const float* W2s = W2; const float* W2v = W2 + F_*F_;
  const float* W2p = W2 + 2*F_*F_; const float* W2q = W2 + 3*F_*F_;
  float os_ = b2v[f], ov0=0.f, ov1=0.f, ov2=0.f, ops_=0.f, opv0=0.f, opv1=0.f, opv2=0.f;
#pragma unroll
  for (int fp = 0; fp < F_; ++fp) {
    float w_s = W2s[fp*F_+f], w_v = W2v[fp*F_+f], w_p = W2p[fp*F_+f], w_q = W2q[fp*F_+f];
    os_  += __shfl(hs, fp, 32)*w_s;
    ov0  += __shfl(hv0, fp, 32)*w_v;
    ov1  += __shfl(hv1, fp, 32)*w_v;
    ov2  += __shfl(hv2, fp, 32)*w_v;
    ops_ += __shfl(hps, fp, 32)*w_p;
    opv0 += __shfl(hpv0, fp, 32)*w_q;
    opv1 += __shfl(hpv1, fp, 32)*w_q;
    opv2 += __shfl(hpv2, fp, 32)*w_q;
  }
  s[ib] += os_;
  v[vb] += ov0; v[vb+F_] += ov1; v[vb+2*F_] += ov2;
  ps[ib] += ops_;
  pv[vb] += opv0; pv[vb+F_] += opv1; pv[vb+2*F_] += opv2;
}

// ---------------- forward last (scalar) pass ----------------
__global__ __launch_bounds__(64) void edge_fwd_last_csr(
    const int* __restrict__ ord_d,
    const int* __restrict__ dst_off, const int* __restrict__ dst_perm,
    const int* __restrict__ src,
    const float* __restrict__ rd, const float* __restrict__ u3,
    const float* __restrict__ Wb0, const float* __restrict__ Wb1, const float* __restrict__ pwl,
    const float* __restrict__ s, const float* __restrict__ v, float* __restrict__ ys) {
  int gid = blockIdx.x * 64 + threadIdx.x;
  int n = ord_d[gid >> 5];
  int f = gid & 31;
  float wb0[K_], wb1[K_];
#pragma unroll
  for (int k = 0; k < K_; ++k) { wb0[k] = Wb0[k*F_+f]; wb1[k] = Wb1[k*F_+f]; }
  float p0 = pwl[f], p1 = pwl[F_+f];
  float m = 0.f;
  int j0 = dst_off[n], j1 = dst_off[n+1];
  for (int j = j0; j < j1; ++j) {
    int e = dst_perm[j];
    int ns = src[e];
    float radl = (f < K_) ? rd[(size_t)e*32 + f] : 0.f;
    float q0 = 0.f, q1 = 0.f;
#pragma unroll
    for (int k = 0; k < K_; ++k) {
      float rk = __shfl(radl, k, 32);
      q0 += rk * wb0[k];
      q1 += rk * wb1[k];
    }
    float u0 = u3[(size_t)e*3+0], u1 = u3[(size_t)e*3+1], u2 = u3[(size_t)e*3+2];
    float se = s[(size_t)ns*F_+f];
    size_t vb = (size_t)ns*3*F_;
    float vu = v[vb+f]*u0 + v[vb+F_+f]*u1 + v[vb+2*F_+f]*u2;
    m += p0*se*q0 + p1*vu*q1;
  }
  ys[(size_t)n*F_+f] = m;
}

__global__ __launch_bounds__(256) void node_fwd_last_kernel(
    float* __restrict__ s, const float* __restrict__ ys,
    const float* __restrict__ W1, const float* __restrict__ b1v,
    const float* __restrict__ W2, const float* __restrict__ b2v,
    float* __restrict__ a_l, const float* __restrict__ w_out,
    const float* __restrict__ ebias, const int* __restrict__ Z,
    const int* __restrict__ bseg, float* __restrict__ energy) {
  __shared__ float bins[B_];
  int tid = threadIdx.x;
  if (tid < B_) bins[tid] = 0.f;
  __syncthreads();
  int gid = blockIdx.x * 256 + tid;
  int n = gid >> 5, f = gid & 31;
  float y0 = s[gid] + ys[gid];
  float a = b1v[f];
#pragma unroll
  for (int fp = 0; fp < F_; ++fp) a += __shfl(y0, fp, 32) * W1[fp*F_+f];
  a_l[gid] = a;
  float g = sigm(a);
  float h = a * g;
  float o = b2v[f];
#pragma unroll
  for (int fp = 0; fp < F_; ++fp) o += __shfl(h, fp, 32) * W2[fp*F_+f];
  float sn = s[gid] + o;
  s[gid] = sn;
  float c = sn * w_out[f];
#pragma unroll
  for (int off = 16; off > 0; off >>= 1) c += __shfl_xor(c, off, 32);
  if (f == 0) {
    c += ebias[Z[n]];
    atomicAdd(&bins[bseg[n]], c);
  }
  __syncthreads();
  if (tid < B_) atomicAdd(&energy[tid], bins[tid]);
}

// ---------------- backward last (scalar) pass ----------------
__global__ __launch_bounds__(256) void b1_last_kernel(
    float* __restrict__ s, const float* __restrict__ a_l,
    const float* __restrict__ W1, const float* __restrict__ W2, const float* __restrict__ b2v,
    float* __restrict__ Gs, float* __restrict__ ys) {
  int gid = blockIdx.x * 256 + threadIdx.x;
  int f = gid & 31;
  float a = a_l[gid];
  float g = sigm(a);
  float h = a * g;
  float o = b2v[f];
#pragma unroll
  for (int fp = 0; fp < F_; ++fp) o += __shfl(h, fp, 32) * W2[fp*F_+f];
  s[gid] -= o;                       // reconstruct s_4
  float gso = Gs[gid];
  float gh = 0.f;
#pragma unroll
  for (int fp = 0; fp < F_; ++fp) gh += __shfl(gso, fp, 32) * W2[f*F_+fp];
  float ga = gh * (g + a*g*(1.f - g));
  float gy = 0.f;
#pragma unroll
  for (int fp = 0; fp < F_; ++fp) gy += __shfl(ga, fp, 32) * W1[f*F_+fp];
  ys[gid] = gy;
  Gs[gid] = gso + gy;
}

// merged backward last edge pass: warp per SRC node (own state local, gather dst grads)
__global__ __launch_bounds__(64) void b2m_last_kernel(
    const int* __restrict__ ord_s,
    const int* __restrict__ src_off, const int* __restrict__ src_perm,
    const int* __restrict__ dst,
    const float* __restrict__ rd, const float* __restrict__ u3,
    const float* __restrict__ Wb0, const float* __restrict__ Wb1, const float* __restrict__ pwl,
    const float* __restrict__ s, const float* __restrict__ v, const float* __restrict__ ysg,
    float* __restrict__ Gs, float* __restrict__ Gv,
    float* __restrict__ grad_r, float* __restrict__ grad_u) {
  int gid = blockIdx.x * 64 + threadIdx.x;
  int n = ord_s[gid >> 5];
  int f = gid & 31;
  float wb0[K_], wb1[K_];
#pragma unroll
  for (int k = 0; k < K_; ++k) { wb0[k] = Wb0[k*F_+f]; wb1[k] = Wb1[k*F_+f]; }
  float p0 = pwl[f], p1 = pwl[F_+f];
  size_t sb = (size_t)n*F_, svb = (size_t)n*3*F_;
  float se = s[sb+f];
  float ve0 = v[svb+f], ve1 = v[svb+F_+f], ve2 = v[svb+2*F_+f];
  float ags = 0.f, agv0 = 0.f, agv1 = 0.f, agv2 = 0.f;
  int j0 = src_off[n], j1 = src_off[n+1];
  for (int j = j0; j < j1; ++j) {
    int e = src_perm[j];
    int nd = dst[e];
    float rdl = rd[(size_t)e*32 + f];   // f<16: rad_f ; f>=16: drad_{f-16}
    float q0 = 0.f, q1 = 0.f, w0 = 0.f, w1 = 0.f;
#pragma unroll
    for (int k = 0; k < K_; ++k) {
      float rk = __shfl(rdl, k, 32);
      float dk = __shfl(rdl, k + 16, 32);
      q0 += rk * wb0[k]; q1 += rk * wb1[k];
      w0 += dk * wb0[k]; w1 += dk * wb1[k];
    }
    float u0 = u3[(size_t)e*3+0], u1 = u3[(size_t)e*3+1], u2 = u3[(size_t)e*3+2];
    float gm = ysg[(size_t)nd*F_+f];
    ags += p0*q0*gm;
    float t1 = p1*q1*gm;
    agv0 += t1*u0; agv1 += t1*u1; agv2 += t1*u2;
    float vu = ve0*u0 + ve1*u1 + ve2*u2;
    float gq0 = p0*se*gm;
    float gq1 = p1*vu*gm;
    float grl = gq0*w0 + gq1*w1;
    float gu0 = t1*ve0, gu1 = t1*ve1, gu2 = t1*ve2;
#pragma unroll
    for (int off = 16; off > 0; off >>= 1) {
      grl += __shfl_xor(grl, off, 32);
      gu0 += __shfl_xor(gu0, off, 32);
      gu1 += __shfl_xor(gu1, off, 32);
      gu2 += __shfl_xor(gu2, off, 32);
    }
    if (f == 0) grad_r[e] = grl;                  // first writer of the backward chain
    if (f < 3) grad_u[(size_t)e*3+f] = (f==0 ? gu0 : (f==1 ? gu1 : gu2));
  }
  Gs[sb+f] += ags;
  Gv[svb+f] += agv0; Gv[svb+F_+f] += agv1; Gv[svb+2*F_+f] += agv2;
}

// ---------------- backward node MLP (full equivariant) ----------------
__global__ __launch_bounds__(256) void b1_kernel(
    float* __restrict__ s, float* __restrict__ v, float* __restrict__ ps, float* __restrict__ pv,
    const float* __restrict__ a_s, const float* __restrict__ a_v,
    const float* __restrict__ a_ps, const float* __restrict__ a_pv,
    const float* __restrict__ W1, const float* __restrict__ W2, const float* __restrict__ b2v,
    float* __restrict__ Gs, float* __restrict__ Gv, float* __restrict__ Gps, float* __restrict__ Gpv,
    float* __restrict__ ys, float* __restrict__ yv, float* __restrict__ yps, float* __restrict__ ypv) {
  int gid = blockIdx.x * 256 + threadIdx.x;
  int n = gid >> 5, f = gid & 31;
  size_t ib = gid;
  size_t vb = (size_t)n*3*F_ + f;
  float as_ = a_s[ib], av0 = a_v[vb], av1 = a_v[vb+F_], av2 = a_v[vb+2*F_];
  float aps_ = a_ps[ib], apv0 = a_pv[vb], apv1 = a_pv[vb+F_], apv2 = a_pv[vb+2*F_];
  float g = sigm(as_);
  float gp = g * (1.f - g);
  float hs=as_*g, hv0=av0*g, hv1=av1*g, hv2=av2*g, hps=aps_*g, hpv0=apv0*g, hpv1=apv1*g, hpv2=apv2*g;
  const float* W2s = W2; const float* W2v = W2 + F_*F_;
  const float* W2p = W2 + 2*F_*F_; const float* W2q = W2 + 3*F_*F_;
  const float* W1s = W1; const float* W1v = W1 + F_*F_;
  const float* W1p = W1 + 2*F_*F_; const float* W1q = W1 + 3*F_*F_;
  float os_ = b2v[f], ov0=0.f, ov1=0.f, ov2=0.f, ops_=0.f, opv0=0.f, opv1=0.f, opv2=0.f;
#pragma unroll
  for (int fp = 0; fp < F_; ++fp) {
    float w_s = W2s[fp*F_+f], w_v = W2v[fp*F_+f], w_p = W2p[fp*F_+f], w_q = W2q[fp*F_+f];
    os_  += __shfl(hs, fp, 32)*w_s;
    ov0  += __shfl(hv0, fp, 32)*w_v;
    ov1  += __shfl(hv1, fp, 32)*w_v;
    ov2  += __shfl(hv2, fp, 32)*w_v;
    ops_ += __shfl(hps, fp, 32)*w_p;
    opv0 += __shfl(hpv0, fp, 32)*w_q;
    opv1 += __shfl(hpv1, fp, 32)*w_q;
    opv2 += __shfl(hpv2, fp, 32)*w_q;
  }
  s[ib] -= os_;
  v[vb] -= ov0; v[vb+F_] -= ov1; v[vb+2*F_] -= ov2;
  ps[ib] -= ops_;
  pv[vb] -= opv0; pv[vb+F_] -= opv1; pv[vb+2*F_] -= opv2;
  float GsV = Gs[ib], Gv0 = Gv[vb], Gv1 = Gv[vb+F_], Gv2 = Gv[vb+2*F_];
  float GpsV = Gps[ib], Gq0 = Gpv[vb], Gq1 = Gpv[vb+F_], Gq2 = Gpv[vb+2*F_];
  float ghs=0.f, ghv0=0.f, ghv1=0.f, ghv2=0.f, ghps=0.f, ghpv0=0.f, ghpv1=0.f, ghpv2=0.f;
#pragma unroll
  for (int fp = 0; fp < F_; ++fp) {
    float w_s = W2s[f*F_+fp], w_v = W2v[f*F_+fp], w_p = W2p[f*F_+fp], w_q = W2q[f*F_+fp];
    ghs   += __shfl(GsV, fp, 32)*w_s;
    ghv0  += __shfl(Gv0, fp, 32)*w_v;
    ghv1  += __shfl(Gv1, fp, 32)*w_v;
    ghv2  += __shfl(Gv2, fp, 32)*w_v;
    ghps  += __shfl(GpsV, fp, 32)*w_p;
    ghpv0 += __shfl(Gq0, fp, 32)*w_q;
    ghpv1 += __shfl(Gq1, fp, 32)*w_q;
    ghpv2 += __shfl(Gq2, fp, 32)*w_q;
  }
  float gas = ghs*g + (ghs*as_ + ghv0*av0 + ghv1*av1 + ghv2*av2 + ghps*aps_
                       + ghpv0*apv0 + ghpv1*apv1 + ghpv2*apv2) * gp;
  float gav0 = ghv0*g, gav1 = ghv1*g, gav2 = ghv2*g;
  float gaps = ghps*g;
  float gapv0 = ghpv0*g, gapv1 = ghpv1*g, gapv2 = ghpv2*g;
  float gys_=0.f, gyv0=0.f, gyv1=0.f, gyv2=0.f, gyps_=0.f, gypv0=0.f, gypv1=0.f, gypv2=0.f;
#pragma unroll
  for (int fp = 0; fp < F_; ++fp) {
    float w_s = W1s[f*F_+fp], w_v = W1v[f*F_+fp], w_p = W1p[f*F_+fp], w_q = W1q[f*F_+fp];
    gys_  += __shfl(gas, fp, 32)*w_s;
    gyv0  += __shfl(gav0, fp, 32)*w_v;
    gyv1  += __shfl(gav1, fp, 32)*w_v;
    gyv2  += __shfl(gav2, fp, 32)*w_v;
    gyps_ += __shfl(gaps, fp, 32)*w_p;
    gypv0 += __shfl(gapv0, fp, 32)*w_q;
    gypv1 += __shfl(gapv1, fp, 32)*w_q;
    gypv2 += __shfl(gapv2, fp, 32)*w_q;
  }
  ys[ib]=gys_; yv[vb]=gyv0; yv[vb+F_]=gyv1; yv[vb+2*F_]=gyv2;
  yps[ib]=gyps_; ypv[vb]=gypv0; ypv[vb+F_]=gypv1; ypv[vb+2*F_]=gypv2;
  Gs[ib]=GsV+gys_; Gv[vb]=Gv0+gyv0; Gv[vb+F_]=Gv1+gyv1; Gv[vb+2*F_]=Gv2+gyv2;
  Gps[ib]=GpsV+gyps_; Gpv[vb]=Gq0+gypv0; Gpv[vb+F_]=Gq1+gypv1; Gpv[vb+2*F_]=Gq2+gypv2;
}

// ---------------- merged backward edge pass: warp per SRC node ----------------
__global__ __launch_bounds__(64) void b2m_kernel(
    const int* __restrict__ ord_s,
    const int* __restrict__ src_off, const int* __restrict__ src_perm,
    const int* __restrict__ dst,
    const float* __restrict__ rd, const float* __restrict__ u3,
    const float* __restrict__ Wb0, const float* __restrict__ Wb1, const float* __restrict__ pw,
    const float* __restrict__ s, const float* __restrict__ v,
    const float* __restrict__ ps, const float* __restrict__ pv,
    const float* __restrict__ ys, const float* __restrict__ yv,
    const float* __restrict__ yps, const float* __restrict__ ypv,
    float* __restrict__ Gs, float* __restrict__ Gv, float* __restrict__ Gps, float* __restrict__ Gpv,
    float* __restrict__ grad_r, float* __restrict__ grad_u) {
  int gid = blockIdx.x * 64 + threadIdx.x;
  int n = ord_s[gid >> 5];
  int f = gid & 31;
  float wb0[K_], wb1[K_];
#pragma unroll
  for (int k = 0; k < K_; ++k) { wb0[k] = Wb0[k*F_+f]; wb1[k] = Wb1[k*F_+f]; }
  float pw0=pw[f],      pw1=pw[F_+f],   pw2=pw[2*F_+f], pw3=pw[3*F_+f], pw4=pw[4*F_+f];
  float pw5=pw[5*F_+f], pw6=pw[6*F_+f], pw7=pw[7*F_+f], pw8=pw[8*F_+f], pw9=pw[9*F_+f];
  size_t sb = (size_t)n*F_, svb = (size_t)n*3*F_;
  float se = s[sb+f], pse = ps[sb+f];
  float ve0 = v[svb+f], ve1 = v[svb+F_+f], ve2 = v[svb+2*F_+f];
  float pve0 = pv[svb+f], pve1 = pv[svb+F_+f], pve2 = pv[svb+2*F_+f];
  float ase=0.f, apse=0.f;
  float ave0=0.f, ave1=0.f, ave2=0.f, apve0=0.f, apve1=0.f, apve2=0.f;
  int j0 = src_off[n], j1 = src_off[n+1];
  for (int j = j0; j < j1; ++j) {
    int e = src_perm[j];
    int nd = dst[e];
    float rdl = rd[(size_t)e*32 + f];
    float q0 = 0.f, q1 = 0.f, w0 = 0.f, w1 = 0.f;
#pragma unroll
    for (int k = 0; k < K_; ++k) {
      float rk = __shfl(rdl, k, 32);
      float dk = __shfl(rdl, k + 16, 32);
      q0 += rk * wb0[k]; q1 += rk * wb1[k];
      w0 += dk * wb0[k]; w1 += dk * wb1[k];
    }
    float u0 = u3[(size_t)e*3+0], u1 = u3[(size_t)e*3+1], u2 = u3[(size_t)e*3+2];
    size_t db = (size_t)nd*F_, dvb = (size_t)nd*3*F_;
    float gms = ys[db+f];
    float gmv0 = yv[dvb+f], gmv1 = yv[dvb+F_+f], gmv2 = yv[dvb+2*F_+f];
    float gmps = yps[db+f];
    float gmpv0 = ypv[dvb+f], gmpv1 = ypv[dvb+F_+f], gmpv2 = ypv[dvb+2*F_+f];
    float udgmv  = u0*gmv0 + u1*gmv1 + u2*gmv2;
    float udgmpv = u0*gmpv0 + u1*gmpv1 + u2*gmpv2;
    float uxgmpv0 = u1*gmpv2 - u2*gmpv1, uxgmpv1 = u2*gmpv0 - u0*gmpv2, uxgmpv2 = u0*gmpv1 - u1*gmpv0;
    float uxgmv0  = u1*gmv2 - u2*gmv1,   uxgmv1  = u2*gmv0 - u0*gmv2,   uxgmv2  = u0*gmv1 - u1*gmv0;
    // own-state (source) grads — accumulate locally
    ase  += pw0*q0*gms  + pw5*q1*udgmv;
    apse += pw2*q0*gmps + pw8*q1*udgmpv;
    ave0 += pw1*u0*q1*gms + pw4*q0*gmv0 + pw9*q1*uxgmpv0;
    ave1 += pw1*u1*q1*gms + pw4*q0*gmv1 + pw9*q1*uxgmpv1;
    ave2 += pw1*u2*q1*gms + pw4*q0*gmv2 + pw9*q1*uxgmpv2;
    apve0 += pw3*u0*q1*gmps + pw7*q0*gmpv0 + pw6*q1*uxgmv0;
    apve1 += pw3*u1*q1*gmps + pw7*q0*gmpv1 + pw6*q1*uxgmv1;
    apve2 += pw3*u2*q1*gmps + pw7*q0*gmpv2 + pw6*q1*uxgmv2;
    // basis grads (need own state x dst grads)
    float vu  = ve0*u0 + ve1*u1 + ve2*u2;
    float pvu = pve0*u0 + pve1*u1 + pve2*u2;
    float cpu0 = pve1*u2 - pve2*u1, cpu1 = pve2*u0 - pve0*u2, cpu2 = pve0*u1 - pve1*u0;
    float cvu0 = ve1*u2 - ve2*u1,  cvu1 = ve2*u0 - ve0*u2,  cvu2 = ve0*u1 - ve1*u0;
    float gq0 = pw0*se*gms + pw2*pse*gmps
              + pw4*(ve0*gmv0 + ve1*gmv1 + ve2*gmv2)
              + pw7*(pve0*gmpv0 + pve1*gmpv1 + pve2*gmpv2);
    float gq1 = pw1*vu*gms + pw3*pvu*gmps + pw5*se*udgmv
              + pw6*(cpu0*gmv0 + cpu1*gmv1 + cpu2*gmv2)
              + pw8*pse*udgmpv
              + pw9*(cvu0*gmpv0 + cvu1*gmpv1 + cvu2*gmpv2);
    float grl = gq0*w0 + gq1*w1;   // dL/dr contribution (projected through drad)
    float gmvxpve0 = gmv1*pve2 - gmv2*pve1, gmvxpve1 = gmv2*pve0 - gmv0*pve2, gmvxpve2 = gmv0*pve1 - gmv1*pve0;
    float gmpvxve0 = gmpv1*ve2 - gmpv2*ve1, gmpvxve1 = gmpv2*ve0 - gmpv0*ve2, gmpvxve2 = gmpv0*ve1 - gmpv1*ve0;
    float gu0 = q1*(pw1*gms*ve0 + pw3*gmps*pve0 + pw5*se*gmv0 + pw6*gmvxpve0 + pw8*pse*gmpv0 + pw9*gmpvxve0);
    float gu1 = q1*(pw1*gms*ve1 + pw3*gmps*pve1 + pw5*se*gmv1 + pw6*gmvxpve1 + pw8*pse*gmpv1 + pw9*gmpvxve1);
    float gu2 = q1*(pw1*gms*ve2 + pw3*gmps*pve2 + pw5*se*gmv2 + pw6*gmvxpve2 + pw8*pse*gmpv2 + pw9*gmpvxve2);
#pragma unroll
    for (int off = 16; off > 0; off >>= 1) {
      grl += __shfl_xor(grl, off, 32);
      gu0 += __shfl_xor(gu0, off, 32);
      gu1 += __shfl_xor(gu1, off, 32);
      gu2 += __shfl_xor(gu2, off, 32);
    }
    if (f == 0) grad_r[e] += grl;
    if (f < 3) grad_u[(size_t)e*3+f] += (f==0 ? gu0 : (f==1 ? gu1 : gu2));
  }
  Gs[sb+f]  += ase;
  Gps[sb+f] += apse;
  Gv[svb+f] += ave0;  Gv[svb+F_+f] += ave1;  Gv[svb+2*F_+f] += ave2;
  Gpv[svb+f] += apve0; Gpv[svb+F_+f] += apve1; Gpv[svb+2*F_+f] += apve2;
}

// ---------------- basis backward: (grad_r, grad_u) -> forces ----------------
__global__ void basis_bwd_kernel(const int* __restrict__ dst, const int* __restrict__ src,
                                 const float* __restrict__ rr, const float* __restrict__ u3,
                                 const float* __restrict__ grad_r, const float* __restrict__ grad_u,
                                 float* __restrict__ forces) {
  int e = blockIdx.x * blockDim.x + threadIdx.x;
  if (e >= E_) return;
  float r = rr[e];
  float u0 = u3[(size_t)e*3+0], u1 = u3[(size_t)e*3+1], u2 = u3[(size_t)e*3+2];
  float gr = grad_r[e];
  float g0 = grad_u[(size_t)e*3+0], g1 = grad_u[(size_t)e*3+1], g2 = grad_u[(size_t)e*3+2];
  float gdu = g0*u0 + g1*u1 + g2*u2;
  float invr = 1.f / r;
  float gd0 = gr*u0 + (g0 - gdu*u0)*invr;
  float gd1 = gr*u1 + (g1 - gdu*u1)*invr;
  float gd2 = gr*u2 + (g2 - gdu*u2)*invr;
  int ns = src[e], nd = dst[e];
  atomicAdd(&forces[(size_t)ns*3+0], gd0);
  atomicAdd(&forces[(size_t)ns*3+1], gd1);
  atomicAdd(&forces[(size_t)ns*3+2], gd2);
  atomicAdd(&forces[(size_t)nd*3+0], -gd0);
  atomicAdd(&forces[(size_t)nd*3+1], -gd1);
  atomicAdd(&forces[(size_t)nd*3+2], -gd2);
}

// ---------------- host launcher ----------------
extern "C" void kernel_launch(void* const* d_in, const int* in_sizes, int n_in,
                              void* d_out, int out_size, void* d_ws, size_t ws_size,
                              hipStream_t stream) {
  const int*   Z     = (const int*)d_in[0];
  const float* pos   = (const float*)d_in[1];
  const int*   dst   = (const int*)d_in[2];
  const int*   src   = (const int*)d_in[3];
  const int*   bseg  = (const int*)d_in[4];
  const float* embed = (const float*)d_in[6];
  const float* Wb0   = (const float*)d_in[7];
  const float* Wb1   = (const float*)d_in[8];
  const float* pw    = (const float*)d_in[9];
  const float* Wd1   = (const float*)d_in[10];
  const float* bd1   = (const float*)d_in[11];
  const float* Wd2   = (const float*)d_in[12];
  const float* bd2   = (const float*)d_in[13];
  const float* Wb0l  = (const float*)d_in[14];
  const float* Wb1l  = (const float*)d_in[15];
  const float* pwl   = (const float*)d_in[16];
  const float* Wd1l  = (const float*)d_in[17];
  const float* bd1l  = (const float*)d_in[18];
  const float* Wd2l  = (const float*)d_in[19];
  const float* bd2l  = (const float*)d_in[20];
  const float* w_out = (const float*)d_in[21];
  const float* ebias = (const float*)d_in[22];

  float* out = (float*)d_out;
  float* energy = out;          // (B,)
  float* forces = out + B_;     // (N,3)

  float* ws = nullptr;
  (void)hipGetSymbolAddress((void**)&ws, HIP_SYMBOL(g_ws));

  const size_t NF = (size_t)N_ * F_;
  const size_t NV = (size_t)N_ * 3 * F_;
  float* rd       = ws;                       // E*32 (rad | drad)
  float* u3       = rd + (size_t)E_*32;       // E*3
  float* rr       = u3 + (size_t)E_*3;        // E
  float* s        = rr + E_;                  // N*F
  float* v        = s + NF;                   // N*3F
  float* ps       = v + NV;                   // N*F
  float* pv       = ps + NF;                  // N*3F
  float* ys       = pv + NV;                  // N*F
  float* yv       = ys + NF;                  // N*3F
  float* yps      = yv + NV;                  // N*F
  float* ypv      = yps + NF;                 // N*3F
  float* Gs       = ypv + NV;                 // N*F
  float* Gv       = Gs + NF;                  // N*3F
  float* Gps      = Gv + NV;                  // N*F
  float* Gpv      = Gps + NF;                 // N*3F
  float* grad_r   = Gpv + NV;                 // E
  float* grad_u   = grad_r + E_;              // E*3
  float* a_s      = grad_u + (size_t)E_*3;    // 4*N*F
  float* a_v      = a_s + 4*NF;               // 4*N*3F
  float* a_ps     = a_v + 4*NV;               // 4*N*F
  float* a_pv     = a_ps + 4*NF;              // 4*N*3F
  float* a_l      = a_pv + 4*NV;              // N*F
  // int region (CSR + sort)
  int* iws        = (int*)(a_l + NF);
  int* cntd       = iws;                      // N
  int* cnts       = cntd + N_;                // N
  int* dst_off    = cnts + N_;                // N+1
  int* src_off    = dst_off + (N_+1);         // N+1
  int* dst_perm   = src_off + (N_+1);         // E
  int* src_perm   = dst_perm + E_;            // E
  int* curd       = src_perm + E_;            // N
  int* curs       = curd + N_;                // N
  int* binc       = curs + N_;                // 128
  int* bcur       = binc + 128;               // 128
  int* ord_d      = bcur + 128;               // N
  int* ord_s      = ord_d + N_;               // N

  const int TB = 256;
  const int nodeBlocks = (int)(NF / TB);             // 6250
  const int warpBlocks = (int)((size_t)N_ * 32 / 64); // 25000 (64-thr CSR kernels)
  const int eThreadBlocks = (E_ + TB - 1) / TB;      // 1563
  const int nThreadBlocks = (N_ + TB - 1) / TB;      // 196

  // ---- CSR build + degree sort ----
  fill_int_kernel<<<256, TB, 0, stream>>>(cntd, (size_t)2*N_, 0);
  fill_int_kernel<<<1, 128, 0, stream>>>(binc, 128, 0);
  hist_kernel<<<eThreadBlocks, TB, 0, stream>>>(dst, src, cntd, cnts);
  scan_kernel<<<2, 1024, 0, stream>>>(cntd, cnts, dst_off, src_off);
  cursor_init_kernel<<<nThreadBlocks, TB, 0, stream>>>(dst_off, src_off, curd, curs);
  scatter_kernel<<<eThreadBlocks, TB, 0, stream>>>(dst, src, curd, curs, dst_perm, src_perm);
  sort_hist_kernel<<<nThreadBlocks, TB, 0, stream>>>(dst_off, src_off, binc);
  sort_scan_kernel<<<1, 64, 0, stream>>>(binc, bcur);
  sort_scatter_kernel<<<nThreadBlocks, TB, 0, stream>>>(dst_off, src_off, bcur, ord_d, ord_s);

  // ---- init state + geometry ----
  fill_kernel<<<2048, TB, 0, stream>>>(v, 7*NF, 0.f);  // v,ps,pv = 0
  init_embed_kernel<<<nodeBlocks, TB, 0, stream>>>(s, embed, Z);
  geom_kernel<<<eThreadBlocks, TB, 0, stream>>>(pos, dst, src, rd, u3, rr);

  // ---- 4 full equivariant passes ----
  for (int i = 0; i < 4; ++i) {
    edge_fwd_csr<<<warpBlocks, 64, 0, stream>>>(
        ord_d, dst_off, dst_perm, src, rd, u3,
        Wb0 + (size_t)i*K_*F_, Wb1 + (size_t)i*K_*F_, pw + (size_t)i*10*F_,
        s, v, ps, pv, ys, yv, yps, ypv);
    node_fwd_kernel<<<nodeBlocks, TB, 0, stream>>>(
        s, v, ps, pv, ys, yv, yps, ypv,
        Wd1 + (size_t)i*4*F_*F_, bd1 + (size_t)i*F_,
        Wd2 + (size_t)i*4*F_*F_, bd2 + (size_t)i*F_,
        a_s + i*NF, a_v + i*NV, a_ps + i*NF, a_pv + i*NV);
  }

  // ---- last scalar pass ----
  fill_kernel<<<592, TB, 0, stream>>>(out, (size_t)(B_ + N_*3), 0.f);
  edge_fwd_last_csr<<<warpBlocks, 64, 0, stream>>>(
      ord_d, dst_off, dst_perm, src, rd, u3, Wb0l, Wb1l, pwl, s, v, ys);
  node_fwd_last_kernel<<<nodeBlocks, TB, 0, stream>>>(
      s, ys, Wd1l, bd1l, Wd2l, bd2l, a_l, w_out, ebias, Z, bseg, energy);

  // ---- backward init ----
  init_gs_kernel<<<nodeBlocks, TB, 0, stream>>>(Gs, w_out);
  fill_kernel<<<2048, TB, 0, stream>>>(Gv, 7*NF, 0.f);

  // ---- last pass backward (writes grad_r/grad_u, no fill needed) ----
  b1_last_kernel<<<nodeBlocks, TB, 0, stream>>>(s, a_l, Wd1l, Wd2l, bd2l, Gs, ys);
  b2m_last_kernel<<<warpBlocks, 64, 0, stream>>>(
      ord_s, src_off, src_perm, dst, rd, u3, Wb0l, Wb1l, pwl, s, v, ys,
      Gs, Gv, grad_r, grad_u);

  // ---- 4 full passes backward ----
  for (int i = 3; i >= 0; --i) {
    b1_kernel<<<nodeBlocks, TB, 0, stream>>>(
        s, v, ps, pv,
        a_s + i*NF, a_v + i*NV, a_ps + i*NF, a_pv + i*NV,
        Wd1 + (size_t)i*4*F_*F_, Wd2 + (size_t)i*4*F_*F_, bd2 + (size_t)i*F_,
        Gs, Gv, Gps, Gpv, ys, yv, yps, ypv);
    b2m_kernel<<<warpBlocks, 64, 0, stream>>>(
        ord_s, src_off, src_perm, dst, rd, u3,
        Wb0 + (size_t)i*K_*F_, Wb1 + (size_t)i*K_*F_, pw + (size_t)i*10*F_,
        s, v, ps, pv, ys, yv, yps, ypv, Gs, Gv, Gps, Gpv, grad_r, grad_u);
  }

  // ---- basis backward -> forces ----
  basis_bwd_kernel<<<eThreadBlocks, TB, 0, stream>>>(
      dst, src, rr, u3, grad_r, grad_u, forces);
}

// Round 8
// 3570.757 us; speedup vs baseline: 1.7603x; 1.1581x over previous
//
#include <hip/hip_runtime.h>
#include <math.h>

namespace {
constexpr int N_ = 50000;
constexpr int E_ = 400000;
constexpr int F_ = 32;
constexpr int K_ = 16;
constexpr int B_ = 10;
constexpr float CUT_ = 10.0f;
constexpr float EPS_ = 1e-8f;
constexpr size_t WS_FLOATS = 108500000;
}

// Static device scratch (d_ws size unknown). ~434 MB BSS.
__device__ float g_ws[WS_FLOATS];

__constant__ float c_binom[K_] = {1.f,15.f,105.f,455.f,1365.f,3003.f,5005.f,6435.f,
                                  6435.f,5005.f,3003.f,1365.f,455.f,105.f,15.f,1.f};

__device__ __forceinline__ float sigm(float x) { return 1.f / (1.f + expf(-x)); }

// ---------------- utility fills ----------------
__global__ void fill_kernel(float* __restrict__ p, size_t n, float v) {
  size_t i = (size_t)blockIdx.x * blockDim.x + threadIdx.x;
  size_t st = (size_t)gridDim.x * blockDim.x;
  for (; i < n; i += st) p[i] = v;
}

__global__ void fill_int_kernel(int* __restrict__ p, size_t n, int v) {
  size_t i = (size_t)blockIdx.x * blockDim.x + threadIdx.x;
  size_t st = (size_t)gridDim.x * blockDim.x;
  for (; i < n; i += st) p[i] = v;
}

__global__ void init_embed_kernel(float* __restrict__ s, const float* __restrict__ embed,
                                  const int* __restrict__ Z) {
  int gid = blockIdx.x * blockDim.x + threadIdx.x;
  int n = gid >> 5, f = gid & 31;
  s[gid] = embed[Z[n] * F_ + f];
}

__global__ void init_gs_kernel(float* __restrict__ Gs, const float* __restrict__ w_out) {
  int gid = blockIdx.x * blockDim.x + threadIdx.x;
  Gs[gid] = -w_out[gid & 31];
}

// ---------------- CSR build ----------------
__global__ void hist_kernel(const int* __restrict__ dst, const int* __restrict__ src,
                            int* __restrict__ cntd, int* __restrict__ cnts) {
  int e = blockIdx.x * blockDim.x + threadIdx.x;
  if (e < E_) { atomicAdd(&cntd[dst[e]], 1); atomicAdd(&cnts[src[e]], 1); }
}

__global__ __launch_bounds__(1024) void scan_kernel(
    const int* __restrict__ cntd, const int* __restrict__ cnts,
    int* __restrict__ offd, int* __restrict__ offs) {
  const int* cnt = blockIdx.x ? cnts : cntd;
  int* off = blockIdx.x ? offs : offd;
  __shared__ int part[1024];
  int tid = threadIdx.x;
  const int CH = (N_ + 1023) / 1024;  // 49
  int base = tid * CH;
  int sum = 0;
  for (int i = 0; i < CH; ++i) { int j = base + i; if (j < N_) sum += cnt[j]; }
  part[tid] = sum; __syncthreads();
  for (int d = 1; d < 1024; d <<= 1) {
    int t = (tid >= d) ? part[tid - d] : 0; __syncthreads();
    part[tid] += t; __syncthreads();
  }
  int run = (tid == 0) ? 0 : part[tid - 1];
  for (int i = 0; i < CH; ++i) {
    int j = base + i;
    if (j <= N_) { off[j] = run; if (j < N_) run += cnt[j]; }
  }
}

__global__ void cursor_init_kernel(const int* __restrict__ offd, const int* __restrict__ offs,
                                   int* __restrict__ curd, int* __restrict__ curs) {
  int i = blockIdx.x * blockDim.x + threadIdx.x;
  if (i < N_) { curd[i] = offd[i]; curs[i] = offs[i]; }
}

__global__ void scatter_kernel(const int* __restrict__ dst, const int* __restrict__ src,
                               int* __restrict__ curd, int* __restrict__ curs,
                               int* __restrict__ permd, int* __restrict__ perms) {
  int e = blockIdx.x * blockDim.x + threadIdx.x;
  if (e < E_) {
    permd[atomicAdd(&curd[dst[e]], 1)] = e;
    perms[atomicAdd(&curs[src[e]], 1)] = e;
  }
}

// ---------------- degree sort (descending), LDS-privatized ----------------
__global__ __launch_bounds__(256) void sort_hist_kernel(
    const int* __restrict__ offd, const int* __restrict__ offs, int* __restrict__ binc) {
  __shared__ int l[128];
  int tid = threadIdx.x;
  if (tid < 128) l[tid] = 0;
  __syncthreads();
  int n = blockIdx.x * 256 + tid;
  if (n < N_) {
    int bd = 63 - min(offd[n+1] - offd[n], 63);
    atomicAdd(&l[bd], 1);
    int bs = 63 - min(offs[n+1] - offs[n], 63);
    atomicAdd(&l[64 + bs], 1);
  }
  __syncthreads();
  if (tid < 128 && l[tid] > 0) atomicAdd(&binc[tid], l[tid]);
}

__global__ void sort_scan_kernel(const int* __restrict__ binc, int* __restrict__ bcur) {
  int t = threadIdx.x;  // 0: dst side, 1: src side
  if (t < 2) {
    int base = t * 64;
    int run = 0;
    for (int i = 0; i < 64; ++i) { bcur[base + i] = run; run += binc[base + i]; }
  }
}

// block-aggregated: LDS rank + one global atomic per (block,bin)
__global__ __launch_bounds__(256) void sort_scatter_kernel(
    const int* __restrict__ offd, const int* __restrict__ offs,
    int* __restrict__ bcur,
    int* __restrict__ ord_d, int* __restrict__ ord_s) {
  __shared__ int lcnt[128];
  __shared__ int lbase[128];
  int tid = threadIdx.x;
  if (tid < 128) lcnt[tid] = 0;
  __syncthreads();
  int n = blockIdx.x * 256 + tid;
  int bd = 0, bs = 0, rkd = 0, rks = 0;
  bool act = (n < N_);
  if (act) {
    bd = 63 - min(offd[n+1] - offd[n], 63);
    rkd = atomicAdd(&lcnt[bd], 1);
    bs = 64 + 63 - min(offs[n+1] - offs[n], 63);
    rks = atomicAdd(&lcnt[bs], 1);
  }
  __syncthreads();
  if (tid < 128 && lcnt[tid] > 0) lbase[tid] = atomicAdd(&bcur[tid], lcnt[tid]);
  __syncthreads();
  if (act) {
    ord_d[lbase[bd] + rkd] = n;
    ord_s[lbase[bs] + rks] = n;
  }
}

// ---------------- geometry / basis (rad + drad interleaved: rd[e][32]) ----------------
__global__ void geom_kernel(const float* __restrict__ pos, const int* __restrict__ dst,
                            const int* __restrict__ src, float* __restrict__ rd,
                            float* __restrict__ u3, float* __restrict__ rr) {
  int e = blockIdx.x * blockDim.x + threadIdx.x;
  if (e >= E_) return;
  int nd = dst[e], ns = src[e];
  float dx = pos[ns*3+0] - pos[nd*3+0];
  float dy = pos[ns*3+1] - pos[nd*3+1];
  float dz = pos[ns*3+2] - pos[nd*3+2];
  float r = sqrtf(dx*dx + dy*dy + dz*dz + EPS_);
  float t = r / (1.f + r);
  float b = 1.f - t;
  float tp[K_], bp[K_];
  tp[0] = 1.f; bp[0] = 1.f;
#pragma unroll
  for (int k = 1; k < K_; ++k) { tp[k] = tp[k-1]*t; bp[k] = bp[k-1]*b; }
  float cut = 0.f, dcut = 0.f;
  if (r < CUT_) {
    float den = (CUT_ - r) * (CUT_ + r);
    cut = expf(-r*r/den);
    dcut = cut * (-2.f*r*CUT_*CUT_/(den*den));
  }
  float inv1pr = 1.f / (1.f + r);
  float dtdr = inv1pr * inv1pr;
#pragma unroll
  for (int k = 0; k < K_; ++k) {
    float rrk = c_binom[k]*tp[k]*bp[K_-1-k];
    float d1 = (k > 0) ? k*tp[k-1]*bp[K_-1-k] : 0.f;
    float d2 = (k < K_-1) ? (K_-1-k)*tp[k]*bp[K_-2-k] : 0.f;
    float drdt = c_binom[k]*(d1 - d2);
    rd[(size_t)e*32 + k]      = rrk*cut;                     // rad_k
    rd[(size_t)e*32 + 16 + k] = drdt*dtdr*cut + rrk*dcut;    // d(rad_k)/dr
  }
  float invr = 1.f / r;
  u3[(size_t)e*3+0] = dx*invr;
  u3[(size_t)e*3+1] = dy*invr;
  u3[(size_t)e*3+2] = dz*invr;
  rr[e] = r;
}

// ---------------- forward edge pass: 32 lanes per dst node, 256-thr blocks ----------------
__global__ __launch_bounds__(256) void edge_fwd_csr(
    const int* __restrict__ ord_d,
    const int* __restrict__ dst_off, const int* __restrict__ dst_perm,
    const int* __restrict__ src,
    const float* __restrict__ rd, const float* __restrict__ u3,
    const float* __restrict__ Wb0, const float* __restrict__ Wb1, const float* __restrict__ pw,
    const float* __restrict__ s, const float* __restrict__ v,
    const float* __restrict__ ps, const float* __restrict__ pv,
    float* __restrict__ ys, float* __restrict__ yv,
    float* __restrict__ yps, float* __restrict__ ypv) {
  int gid = blockIdx.x * 256 + threadIdx.x;
  int n = ord_d[gid >> 5];
  int f = gid & 31;
  float wb0[K_], wb1[K_];
#pragma unroll
  for (int k = 0; k < K_; ++k) { wb0[k] = Wb0[k*F_+f]; wb1[k] = Wb1[k*F_+f]; }
  float pw0=pw[f],      pw1=pw[F_+f],   pw2=pw[2*F_+f], pw3=pw[3*F_+f], pw4=pw[4*F_+f];
  float pw5=pw[5*F_+f], pw6=pw[6*F_+f], pw7=pw[7*F_+f], pw8=pw[8*F_+f], pw9=pw[9*F_+f];
  float ms=0.f, mps=0.f, mv0=0.f, mv1=0.f, mv2=0.f, mpv0=0.f, mpv1=0.f, mpv2=0.f;
  int j0 = dst_off[n], j1 = dst_off[n+1];
  for (int j = j0; j < j1; ++j) {
    int e = dst_perm[j];
    int ns = src[e];
    float radl = (f < K_) ? rd[(size_t)e*32 + f] : 0.f;
    float q0 = 0.f, q1 = 0.f;
#pragma unroll
    for (int k = 0; k < K_; ++k) {
      float rk = __shfl(radl, k, 32);
      q0 += rk * wb0[k];
      q1 += rk * wb1[k];
    }
    float u0 = u3[(size_t)e*3+0], u1 = u3[(size_t)e*3+1], u2 = u3[(size_t)e*3+2];
    size_t sb = (size_t)ns*F_, vb = (size_t)ns*3*F_;
    float se = s[sb+f], pse = ps[sb+f];
    float ve0 = v[vb+f], ve1 = v[vb+F_+f], ve2 = v[vb+2*F_+f];
    float pve0 = pv[vb+f], pve1 = pv[vb+F_+f], pve2 = pv[vb+2*F_+f];
    float vu  = ve0*u0 + ve1*u1 + ve2*u2;
    float pvu = pve0*u0 + pve1*u1 + pve2*u2;
    float cpu0 = pve1*u2 - pve2*u1, cpu1 = pve2*u0 - pve0*u2, cpu2 = pve0*u1 - pve1*u0;
    float cvu0 = ve1*u2 - ve2*u1,  cvu1 = ve2*u0 - ve0*u2,  cvu2 = ve0*u1 - ve1*u0;
    ms  += pw0*se*q0  + pw1*vu*q1;
    mps += pw2*pse*q0 + pw3*pvu*q1;
    mv0 += pw4*ve0*q0 + (pw5*se*u0 + pw6*cpu0)*q1;
    mv1 += pw4*ve1*q0 + (pw5*se*u1 + pw6*cpu1)*q1;
    mv2 += pw4*ve2*q0 + (pw5*se*u2 + pw6*cpu2)*q1;
    mpv0 += pw7*pve0*q0 + (pw8*pse*u0 + pw9*cvu0)*q1;
    mpv1 += pw7*pve1*q0 + (pw8*pse*u1 + pw9*cvu1)*q1;
    mpv2 += pw7*pve2*q0 + (pw8*pse*u2 + pw9*cvu2)*q1;
  }
  size_t db = (size_t)n*F_, dvb = (size_t)n*3*F_;
  ys[db+f] = ms;
  yps[db+f] = mps;
  yv[dvb+f] = mv0;   yv[dvb+F_+f] = mv1;   yv[dvb+2*F_+f] = mv2;
  ypv[dvb+f] = mpv0; ypv[dvb+F_+f] = mpv1; ypv[dvb+2*F_+f] = mpv2;
}

// ---------------- forward node MLP (full equivariant) ----------------
__global__ __launch_bounds__(256) void node_fwd_kernel(
    float* __restrict__ s, float* __restrict__ v, float* __restrict__ ps, float* __restrict__ pv,
    const float* __restrict__ ys, const float* __restrict__ yv,
    const float* __restrict__ yps, const float* __restrict__ ypv,
    const float* __restrict__ W1, const float* __restrict__ b1v,
    const float* __restrict__ W2, const float* __restrict__ b2v,
    float* __restrict__ a_s, float* __restrict__ a_v,
    float* __restrict__ a_ps, float* __restrict__ a_pv) {
  int gid = blockIdx.x * 256 + threadIdx.x;
  int n = gid >> 5, f = gid & 31;
  size_t ib = gid;
  size_t vb = (size_t)n*3*F_ + f;
  float y0s  = s[ib] + ys[ib];
  float y0v0 = v[vb] + yv[vb];
  float y0v1 = v[vb+F_] + yv[vb+F_];
  float y0v2 = v[vb+2*F_] + yv[vb+2*F_];
  float y0ps = ps[ib] + yps[ib];
  float y0pv0 = pv[vb] + ypv[vb];
  float y0pv1 = pv[vb+F_] + ypv[vb+F_];
  float y0pv2 = pv[vb+2*F_] + ypv[vb+2*F_];
  const float* W1s = W1; const float* W1v = W1 + F_*F_;
  const float* W1p = W1 + 2*F_*F_; const float* W1q = W1 + 3*F_*F_;
  float as_ = b1v[f], av0=0.f, av1=0.f, av2=0.f, aps_=0.f, apv0=0.f, apv1=0.f, apv2=0.f;
#pragma unroll
  for (int fp = 0; fp < F_; ++fp) {
    float w_s = W1s[fp*F_+f], w_v = W1v[fp*F_+f], w_p = W1p[fp*F_+f], w_q = W1q[fp*F_+f];
    as_  += __shfl(y0s, fp, 32)*w_s;
    av0  += __shfl(y0v0, fp, 32)*w_v;
    av1  += __shfl(y0v1, fp, 32)*w_v;
    av2  += __shfl(y0v2, fp, 32)*w_v;
    aps_ += __shfl(y0ps, fp, 32)*w_p;
    apv0 += __shfl(y0pv0, fp, 32)*w_q;
    apv1 += __shfl(y0pv1, fp, 32)*w_q;
    apv2 += __shfl(y0pv2, fp, 32)*w_q;
  }
  a_s[ib]=as_; a_v[vb]=av0; a_v[vb+F_]=av1; a_v[vb+2*F_]=av2;
  a_ps[ib]=aps_; a_pv[vb]=apv0; a_pv[vb+F_]=apv1; a_pv[vb+2*F_]=apv2;
  float g = sigm(as_);
  float hs=as_*g, hv0=av0*g, hv1=av1*g, hv2=av2*g, hps=aps_*g, hpv0=apv0*g, hpv1=apv1*g, hpv2=apv2*g;
  const float* W2s = W2; const float* W2v = W2 + F_*F_;
  const float* W2p = W2 + 2*F_*F_; const float* W2q = W2 + 3*F_*F_;
  float os_ = b2v[f], ov0=0.f, ov1=0.f, ov2=0.f, ops_=0.f, opv0=0.f, opv1=0.f, opv2=0.f;
#pragma unroll
  for (int fp = 0; fp < F_; ++fp) {
    float w_s = W2s[fp*F_+f], w_v = W2v[fp*F_+f], w_p = W2p[fp*F_+f], w_q = W2q[fp*F_+f];
    os_  += __shfl(hs, fp, 32)*w_s;
    ov0  += __shfl(hv0, fp, 32)*w_v;
    ov1  += __shfl(hv1, fp, 32)*w_v;
    ov2  += __shfl(hv2, fp, 32)*w_v;
    ops_ += __shfl(hps, fp, 32)*w_p;
    opv0 += __shfl(hpv0, fp, 32)*w_q;
    opv1 += __shfl(hpv1, fp, 32)*w_q;
    opv2 += __shfl(hpv2, fp, 32)*w_q;
  }
  s[ib] += os_;
  v[vb] += ov0; v[vb+F_] += ov1; v[vb+2*F_] += ov2;
  ps[ib] += ops_;
  pv[vb] += opv0; pv[vb+F_] += opv1; pv[vb+2*F_] += opv2;
}

// ---------------- forward last (scalar) pass ----------------
__global__ __launch_bounds__(256) void edge_fwd_last_csr(
    const int* __restrict__ ord_d,
    const int* __restrict__ dst_off, const int* __restrict__ dst_perm,
    const int* __restrict__ src,
    const float* __restrict__ rd, const float* __restrict__ u3,
    const float* __restrict__ Wb0, const float* __restrict__ Wb1, const float* __restrict__ pwl,
    const float* __restrict__ s, const float* __restrict__ v, float* __restrict__ ys) {
  int gid = blockIdx.x * 256 + threadIdx.x;
  int n = ord_d[gid >> 5];
  int f = gid & 31;
  float wb0[K_], wb1[K_];
#pragma unroll
  for (int k = 0; k < K_; ++k) { wb0[k] = Wb0[k*F_+f]; wb1[k] = Wb1[k*F_+f]; }
  float p0 = pwl[f], p1 = pwl[F_+f];
  float m = 0.f;
  int j0 = dst_off[n], j1 = dst_off[n+1];
  for (int j = j0; j < j1; ++j) {
    int e = dst_perm[j];
    int ns = src[e];
    float radl = (f < K_) ? rd[(size_t)e*32 + f] : 0.f;
    float q0 = 0.f, q1 = 0.f;
#pragma unroll
    for (int k = 0; k < K_; ++k) {
      float rk = __shfl(radl, k, 32);
      q0 += rk * wb0[k];
      q1 += rk * wb1[k];
    }
    float u0 = u3[(size_t)e*3+0], u1 = u3[(size_t)e*3+1], u2 = u3[(size_t)e*3+2];
    float se = s[(size_t)ns*F_+f];
    size_t vb = (size_t)ns*3*F_;
    float vu = v[vb+f]*u0 + v[vb+F_+f]*u1 + v[vb+2*F_+f]*u2;
    m += p0*se*q0 + p1*vu*q1;
  }
  ys[(size_t)n*F_+f] = m;
}

__global__ __launch_bounds__(256) void node_fwd_last_kernel(
    float* __restrict__ s, const float* __restrict__ ys,
    const float* __restrict__ W1, const float* __restrict__ b1v,
    const float* __restrict__ W2, const float* __restrict__ b2v,
    float* __restrict__ a_l, const float* __restrict__ w_out,
    const float* __restrict__ ebias, const int* __restrict__ Z,
    const int* __restrict__ bseg, float* __restrict__ energy) {
  __shared__ float bins[B_];
  int tid = threadIdx.x;
  if (tid < B_) bins[tid] = 0.f;
  __syncthreads();
  int gid = blockIdx.x * 256 + tid;
  int n = gid >> 5, f = gid & 31;
  float y0 = s[gid] + ys[gid];
  float a = b1v[f];
#pragma unroll
  for (int fp = 0; fp < F_; ++fp) a += __shfl(y0, fp, 32) * W1[fp*F_+f];
  a_l[gid] = a;
  float g = sigm(a);
  float h = a * g;
  float o = b2v[f];
#pragma unroll
  for (int fp = 0; fp < F_; ++fp) o += __shfl(h, fp, 32) * W2[fp*F_+f];
  float sn = s[gid] + o;
  s[gid] = sn;
  float c = sn * w_out[f];
#pragma unroll
  for (int off = 16; off > 0; off >>= 1) c += __shfl_xor(c, off, 32);
  if (f == 0) {
    c += ebias[Z[n]];
    atomicAdd(&bins[bseg[n]], c);
  }
  __syncthreads();
  if (tid < B_) atomicAdd(&energy[tid], bins[tid]);
}

// ---------------- backward last (scalar) pass ----------------
__global__ __launch_bounds__(256) void b1_last_kernel(
    float* __restrict__ s, const float* __restrict__ a_l,
    const float* __restrict__ W1, const float* __restrict__ W2, const float* __restrict__ b2v,
    float* __restrict__ Gs, float* __restrict__ ys) {
  int gid = blockIdx.x * 256 + threadIdx.x;
  int f = gid & 31;
  float a = a_l[gid];
  float g = sigm(a);
  float h = a * g;
  float o = b2v[f];
#pragma unroll
  for (int fp = 0; fp < F_; ++fp) o += __shfl(h, fp, 32) * W2[fp*F_+f];
  s[gid] -= o;                       // reconstruct s_4
  float gso = Gs[gid];
  float gh = 0.f;
#pragma unroll
  for (int fp = 0; fp < F_; ++fp) gh += __shfl(gso, fp, 32) * W2[f*F_+fp];
  float ga = gh * (g + a*g*(1.f - g));
  float gy = 0.f;
#pragma unroll
  for (int fp = 0; fp < F_; ++fp) gy += __shfl(ga, fp, 32) * W1[f*F_+fp];
  ys[gid] = gy;
  Gs[gid] = gso + gy;
}

// merged backward last edge pass: 32 lanes per SRC node
__global__ __launch_bounds__(256) void b2m_last_kernel(
    const int* __restrict__ ord_s,
    const int* __restrict__ src_off, const int* __restrict__ src_perm,
    const int* __restrict__ dst,
    const float* __restrict__ rd, const float* __restrict__ u3,
    const float* __restrict__ Wb0, const float* __restrict__ Wb1, const float* __restrict__ pwl,
    const float* __restrict__ s, const float* __restrict__ v, const float* __restrict__ ysg,
    float* __restrict__ Gs, float* __restrict__ Gv,
    float* __restrict__ grad_r, float* __restrict__ grad_u) {
  int gid = blockIdx.x * 256 + threadIdx.x;
  int n = ord_s[gid >> 5];
  int f = gid & 31;
  float wb0[K_], wb1[K_];
#pragma unroll
  for (int k = 0; k < K_; ++k) { wb0[k] = Wb0[k*F_+f]; wb1[k] = Wb1[k*F_+f]; }
  float p0 = pwl[f], p1 = pwl[F_+f];
  size_t sb = (size_t)n*F_, svb = (size_t)n*3*F_;
  float se = s[sb+f];
  float ve0 = v[svb+f], ve1 = v[svb+F_+f], ve2 = v[svb+2*F_+f];
  float ags = 0.f, agv0 = 0.f, agv1 = 0.f, agv2 = 0.f;
  int j0 = src_off[n], j1 = src_off[n+1];
  for (int j = j0; j < j1; ++j) {
    int e = src_perm[j];
    int nd = dst[e];
    float rdl = rd[(size_t)e*32 + f];   // f<16: rad_f ; f>=16: drad_{f-16}
    float q0 = 0.f, q1 = 0.f, w0 = 0.f, w1 = 0.f;
#pragma unroll
    for (int k = 0; k < K_; ++k) {
      float rk = __shfl(rdl, k, 32);
      float dk = __shfl(rdl, k + 16, 32);
      q0 += rk * wb0[k]; q1 += rk * wb1[k];
      w0 += dk * wb0[k]; w1 += dk * wb1[k];
    }
    float u0 = u3[(size_t)e*3+0], u1 = u3[(size_t)e*3+1], u2 = u3[(size_t)e*3+2];
    float gm = ysg[(size_t)nd*F_+f];
    ags += p0*q0*gm;
    float t1 = p1*q1*gm;
    agv0 += t1*u0; agv1 += t1*u1; agv2 += t1*u2;
    float vu = ve0*u0 + ve1*u1 + ve2*u2;
    float gq0 = p0*se*gm;
    float gq1 = p1*vu*gm;
    float grl = gq0*w0 + gq1*w1;
    float gu0 = t1*ve0, gu1 = t1*ve1, gu2 = t1*ve2;
#pragma unroll
    for (int off = 16; off > 0; off >>= 1) {
      grl += __shfl_xor(grl, off, 32);
      gu0 += __shfl_xor(gu0, off, 32);
      gu1 += __shfl_xor(gu1, off, 32);
      gu2 += __shfl_xor(gu2, off, 32);
    }
    if (f == 0) grad_r[e] = grl;                  // first writer of the backward chain
    if (f < 3) grad_u[(size_t)e*3+f] = (f==0 ? gu0 : (f==1 ? gu1 : gu2));
  }
  Gs[sb+f] += ags;
  Gv[svb+f] += agv0; Gv[svb+F_+f] += agv1; Gv[svb+2*F_+f] += agv2;
}

// ---------------- backward node MLP (full equivariant) ----------------
__global__ __launch_bounds__(256) void b1_kernel(
    float* __restrict__ s, float* __restrict__ v, float* __restrict__ ps, float* __restrict__ pv,
    const float* __restrict__ a_s, const float* __restrict__ a_v,
    const float* __restrict__ a_ps, const float* __restrict__ a_pv,
    const float* __restrict__ W1, const float* __restrict__ W2, const float* __restrict__ b2v,
    float* __restrict__ Gs, float* __restrict__ Gv, float* __restrict__ Gps, float* __restrict__ Gpv,
    float* __restrict__ ys, float* __restrict__ yv, float* __restrict__ yps, float* __restrict__ ypv) {
  int gid = blockIdx.x * 256 + threadIdx.x;
  int n = gid >> 5, f = gid & 31;
  size_t ib = gid;
  size_t vb = (size_t)n*3*F_ + f;
  float as_ = a_s[ib], av0 = a_v[vb], av1 = a_v[vb+F_], av2 = a_v[vb+2*F_];
  float aps_ = a_ps[ib], apv0 = a_pv[vb], apv1 = a_pv[vb+F_], apv2 = a_pv[vb+2*F_];
  float g = sigm(as_);
  float gp = g * (1.f - g);
  float hs=as_*g, hv0=av0*g, hv1=av1*g, hv2=av2*g, hps=aps_*g, hpv0=apv0*g, hpv1=apv1*g, hpv2=apv2*g;
  const float* W2s = W2; const float* W2v = W2 + F_*F_;
  const float* W2p = W2 + 2*F_*F_; const float* W2q = W2 + 3*F_*F_;
  const float* W1s = W1; const float* W1v = W1 + F_*F_;
  const float* W1p = W1 + 2*F_*F_; const float* W1q = W1 + 3*F_*F_;
  float os_ = b2v[f], ov0=0.f, ov1=0.f, ov2=0.f, ops_=0.f, opv0=0.f, opv1=0.f, opv2=0.f;
#pragma unroll
  for (int fp = 0; fp < F_; ++fp) {
    float w_s = W2s[fp*F_+f], w_v = W2v[fp*F_+f], w_p = W2p[fp*F_+f], w_q = W2q[fp*F_+f];
    os_  += __shfl(hs, fp, 32)*w_s;
    ov0  += __shfl(hv0, fp, 32)*w_v;
    ov1  += __shfl(hv1, fp, 32)*w_v;
    ov2  += __shfl(hv2, fp, 32)*w_v;
    ops_ += __shfl(hps, fp, 32)*w_p;
    opv0 += __shfl(hpv0, fp, 32)*w_q;
    opv1 += __shfl(hpv1, fp, 32)*w_q;
    opv2 += __shfl(hpv2, fp, 32)*w_q;
  }
  s[ib] -= os_;
  v[vb] -= ov0; v[vb+F_] -= ov1; v[vb+2*F_] -= ov2;
  ps[ib] -= ops_;
  pv[vb] -= opv0; pv[vb+F_] -= opv1; pv[vb+2*F_] -= opv2;
  float GsV = Gs[ib], Gv0 = Gv[vb], Gv1 = Gv[vb+F_], Gv2 = Gv[vb+2*F_];
  float GpsV = Gps[ib], Gq0 = Gpv[vb], Gq1 = Gpv[vb+F_], Gq2 = Gpv[vb+2*F_];
  float ghs=0.f, ghv0=0.f, ghv1=0.f, ghv2=0.f, ghps=0.f, ghpv0=0.f, ghpv1=0.f, ghpv2=0.f;
#pragma unroll
  for (int fp = 0; fp < F_; ++fp) {
    float w_s = W2s[f*F_+fp], w_v = W2v[f*F_+fp], w_p = W2p[f*F_+fp], w_q = W2q[f*F_+fp];
    ghs   += __shfl(GsV, fp, 32)*w_s;
    ghv0  += __shfl(Gv0, fp, 32)*w_v;
    ghv1  += __shfl(Gv1, fp, 32)*w_v;
    ghv2  += __shfl(Gv2, fp, 32)*w_v;
    ghps  += __shfl(GpsV, fp, 32)*w_p;
    ghpv0 += __shfl(Gq0, fp, 32)*w_q;
    ghpv1 += __shfl(Gq1, fp, 32)*w_q;
    ghpv2 += __shfl(Gq2, fp, 32)*w_q;
  }
  float gas = ghs*g + (ghs*as_ + ghv0*av0 + ghv1*av1 + ghv2*av2 + ghps*aps_
                       + ghpv0*apv0 + ghpv1*apv1 + ghpv2*apv2) * gp;
  float gav0 = ghv0*g, gav1 = ghv1*g, gav2 = ghv2*g;
  float gaps = ghps*g;
  float gapv0 = ghpv0*g, gapv1 = ghpv1*g, gapv2 = ghpv2*g;
  float gys_=0.f, gyv0=0.f, gyv1=0.f, gyv2=0.f, gyps_=0.f, gypv0=0.f, gypv1=0.f, gypv2=0.f;
#pragma unroll
  for (int fp = 0; fp < F_; ++fp) {
    float w_s = W1s[f*F_+fp], w_v = W1v[f*F_+fp], w_p = W1p[f*F_+fp], w_q = W1q[f*F_+fp];
    gys_  += __shfl(gas, fp, 32)*w_s;
    gyv0  += __shfl(gav0, fp, 32)*w_v;
    gyv1  += __shfl(gav1, fp, 32)*w_v;
    gyv2  += __shfl(gav2, fp, 32)*w_v;
    gyps_ += __shfl(gaps, fp, 32)*w_p;
    gypv0 += __shfl(gapv0, fp, 32)*w_q;
    gypv1 += __shfl(gapv1, fp, 32)*w_q;
    gypv2 += __shfl(gapv2, fp, 32)*w_q;
  }
  ys[ib]=gys_; yv[vb]=gyv0; yv[vb+F_]=gyv1; yv[vb+2*F_]=gyv2;
  yps[ib]=gyps_; ypv[vb]=gypv0; ypv[vb+F_]=gypv1; ypv[vb+2*F_]=gypv2;
  Gs[ib]=GsV+gys_; Gv[vb]=Gv0+gyv0; Gv[vb+F_]=Gv1+gyv1; Gv[vb+2*F_]=Gv2+gyv2;
  Gps[ib]=GpsV+gyps_; Gpv[vb]=Gq0+gypv0; Gpv[vb+F_]=Gq1+gypv1; Gpv[vb+2*F_]=Gq2+gypv2;
}

// ---------------- merged backward edge pass: 32 lanes per SRC node ----------------
__global__ __launch_bounds__(256) void b2m_kernel(
    const int* __restrict__ ord_s,
    const int* __restrict__ src_off, const int* __restrict__ src_perm,
    const int* __restrict__ dst,
    const float* __restrict__ rd, const float* __restrict__ u3,
    const float* __restrict__ Wb0, const float* __restrict__ Wb1, const float* __restrict__ pw,
    const float* __restrict__ s, const float* __restrict__ v,
    const float* __restrict__ ps, const float* __restrict__ pv,
    const float* __restrict__ ys, const float* __restrict__ yv,
    const float* __restrict__ yps, const float* __restrict__ ypv,
    float* __restrict__ Gs, float* __restrict__ Gv, float* __restrict__ Gps, float* __restrict__ Gpv,
    float* __restrict__ grad_r, float* __restrict__ grad_u) {
  int gid = blockIdx.x * 256 + threadIdx.x;
  int n = ord_s[gid >> 5];
  int f = gid & 31;
  float wb0[K_], wb1[K_];
#pragma unroll
  for (int k = 0; k < K_; ++k) { wb0[k] = Wb0[k*F_+f]; wb1[k] = Wb1[k*F_+f]; }
  float pw0=pw[f],      pw1=pw[F_+f],   pw2=pw[2*F_+f], pw3=pw[3*F_+f], pw4=pw[4*F_+f];
  float pw5=pw[5*F_+f], pw6=pw[6*F_+f], pw7=pw[7*F_+f], pw8=pw[8*F_+f], pw9=pw[9*F_+f];
  size_t sb = (size_t)n*F_, svb = (size_t)n*3*F_;
  float se = s[sb+f], pse = ps[sb+f];
  float ve0 = v[svb+f], ve1 = v[svb+F_+f], ve2 = v[svb+2*F_+f];
  float pve0 = pv[svb+f], pve1 = pv[svb+F_+f], pve2 = pv[svb+2*F_+f];
  float ase=0.f, apse=0.f;
  float ave0=0.f, ave1=0.f, ave2=0.f, apve0=0.f, apve1=0.f, apve2=0.f;
  int j0 = src_off[n], j1 = src_off[n+1];
  for (int j = j0; j < j1; ++j) {
    int e = src_perm[j];
    int nd = dst[e];
    float rdl = rd[(size_t)e*32 + f];
    float q0 = 0.f, q1 = 0.f, w0 = 0.f, w1 = 0.f;
#pragma unroll
    for (int k = 0; k < K_; ++k) {
      float rk = __shfl(rdl, k, 32);
      float dk = __shfl(rdl, k + 16, 32);
      q0 += rk * wb0[k]; q1 += rk * wb1[k];
      w0 += dk * wb0[k]; w1 += dk * wb1[k];
    }
    float u0 = u3[(size_t)e*3+0], u1 = u3[(size_t)e*3+1], u2 = u3[(size_t)e*3+2];
    size_t db = (size_t)nd*F_, dvb = (size_t)nd*3*F_;
    float gms = ys[db+f];
    float gmv0 = yv[dvb+f], gmv1 = yv[dvb+F_+f], gmv2 = yv[dvb+2*F_+f];
    float gmps = yps[db+f];
    float gmpv0 = ypv[dvb+f], gmpv1 = ypv[dvb+F_+f], gmpv2 = ypv[dvb+2*F_+f];
    float udgmv  = u0*gmv0 + u1*gmv1 + u2*gmv2;
    float udgmpv = u0*gmpv0 + u1*gmpv1 + u2*gmpv2;
    float uxgmpv0 = u1*gmpv2 - u2*gmpv1, uxgmpv1 = u2*gmpv0 - u0*gmpv2, uxgmpv2 = u0*gmpv1 - u1*gmpv0;
    float uxgmv0  = u1*gmv2 - u2*gmv1,   uxgmv1  = u2*gmv0 - u0*gmv2,   uxgmv2  = u0*gmv1 - u1*gmv0;
    // own-state (source) grads — accumulate locally
    ase  += pw0*q0*gms  + pw5*q1*udgmv;
    apse += pw2*q0*gmps + pw8*q1*udgmpv;
    ave0 += pw1*u0*q1*gms + pw4*q0*gmv0 + pw9*q1*uxgmpv0;
    ave1 += pw1*u1*q1*gms + pw4*q0*gmv1 + pw9*q1*uxgmpv1;
    ave2 += pw1*u2*q1*gms + pw4*q0*gmv2 + pw9*q1*uxgmpv2;
    apve0 += pw3*u0*q1*gmps + pw7*q0*gmpv0 + pw6*q1*uxgmv0;
    apve1 += pw3*u1*q1*gmps + pw7*q0*gmpv1 + pw6*q1*uxgmv1;
    apve2 += pw3*u2*q1*gmps + pw7*q0*gmpv2 + pw6*q1*uxgmv2;
    // basis grads (need own state x dst grads)
    float vu  = ve0*u0 + ve1*u1 + ve2*u2;
    float pvu = pve0*u0 + pve1*u1 + pve2*u2;
    float cpu0 = pve1*u2 - pve2*u1, cpu1 = pve2*u0 - pve0*u2, cpu2 = pve0*u1 - pve1*u0;
    float cvu0 = ve1*u2 - ve2*u1,  cvu1 = ve2*u0 - ve0*u2,  cvu2 = ve0*u1 - ve1*u0;
    float gq0 = pw0*se*gms + pw2*pse*gmps
              + pw4*(ve0*gmv0 + ve1*gmv1 + ve2*gmv2)
              + pw7*(pve0*gmpv0 + pve1*gmpv1 + pve2*gmpv2);
    float gq1 = pw1*vu*gms + pw3*pvu*gmps + pw5*se*udgmv
              + pw6*(cpu0*gmv0 + cpu1*gmv1 + cpu2*gmv2)
              + pw8*pse*udgmpv
              + pw9*(cvu0*gmpv0 + cvu1*gmpv1 + cvu2*gmpv2);
    float grl = gq0*w0 + gq1*w1;   // dL/dr contribution (projected through drad)
    float gmvxpve0 = gmv1*pve2 - gmv2*pve1, gmvxpve1 = gmv2*pve0 - gmv0*pve2, gmvxpve2 = gmv0*pve1 - gmv1*pve0;
    float gmpvxve0 = gmpv1*ve2 - gmpv2*ve1, gmpvxve1 = gmpv2*ve0 - gmpv0*ve2, gmpvxve2 = gmpv0*ve1 - gmpv1*ve0;
    float gu0 = q1*(pw1*gms*ve0 + pw3*gmps*pve0 + pw5*se*gmv0 + pw6*gmvxpve0 + pw8*pse*gmpv0 + pw9*gmpvxve0);
    float gu1 = q1*(pw1*gms*ve1 + pw3*gmps*pve1 + pw5*se*gmv1 + pw6*gmvxpve1 + pw8*pse*gmpv1 + pw9*gmpvxve1);
    float gu2 = q1*(pw1*gms*ve2 + pw3*gmps*pve2 + pw5*se*gmv2 + pw6*gmvxpve2 + pw8*pse*gmpv2 + pw9*gmpvxve2);
#pragma unroll
    for (int off = 16; off > 0; off >>= 1) {
      grl += __shfl_xor(grl, off, 32);
      gu0 += __shfl_xor(gu0, off, 32);
      gu1 += __shfl_xor(gu1, off, 32);
      gu2 += __shfl_xor(gu2, off, 32);
    }
    if (f == 0) grad_r[e] += grl;
    if (f < 3) grad_u[(size_t)e*3+f] += (f==0 ? gu0 : (f==1 ? gu1 : gu2));
  }
  Gs[sb+f]  += ase;
  Gps[sb+f] += apse;
  Gv[svb+f] += ave0;  Gv[svb+F_+f] += ave1;  Gv[svb+2*F_+f] += ave2;
  Gpv[svb+f] += apve0; Gpv[svb+F_+f] += apve1; Gpv[svb+2*F_+f] += apve2;
}

// ---------------- basis backward: (grad_r, grad_u) -> forces ----------------
__global__ void basis_bwd_kernel(const int* __restrict__ dst, const int* __restrict__ src,
                                 const float* __restrict__ rr, const float* __restrict__ u3,
                                 const float* __restrict__ grad_r, const float* __restrict__ grad_u,
                                 float* __restrict__ forces) {
  int e = blockIdx.x * blockDim.x + threadIdx.x;
  if (e >= E_) return;
  float r = rr[e];
  float u0 = u3[(size_t)e*3+0], u1 = u3[(size_t)e*3+1], u2 = u3[(size_t)e*3+2];
  float gr = grad_r[e];
  float g0 = grad_u[(size_t)e*3+0], g1 = grad_u[(size_t)e*3+1], g2 = grad_u[(size_t)e*3+2];
  float gdu = g0*u0 + g1*u1 + g2*u2;
  float invr = 1.f / r;
  float gd0 = gr*u0 + (g0 - gdu*u0)*invr;
  float gd1 = gr*u1 + (g1 - gdu*u1)*invr;
  float gd2 = gr*u2 + (g2 - gdu*u2)*invr;
  int ns = src[e], nd = dst[e];
  atomicAdd(&forces[(size_t)ns*3+0], gd0);
  atomicAdd(&forces[(size_t)ns*3+1], gd1);
  atomicAdd(&forces[(size_t)ns*3+2], gd2);
  atomicAdd(&forces[(size_t)nd*3+0], -gd0);
  atomicAdd(&forces[(size_t)nd*3+1], -gd1);
  atomicAdd(&forces[(size_t)nd*3+2], -gd2);
}

// ---------------- host launcher ----------------
extern "C" void kernel_launch(void* const* d_in, const int* in_sizes, int n_in,
                              void* d_out, int out_size, void* d_ws, size_t ws_size,
                              hipStream_t stream) {
  const int*   Z     = (const int*)d_in[0];
  const float* pos   = (const float*)d_in[1];
  const int*   dst   = (const int*)d_in[2];
  const int*   src   = (const int*)d_in[3];
  const int*   bseg  = (const int*)d_in[4];
  const float* embed = (const float*)d_in[6];
  const float* Wb0   = (const float*)d_in[7];
  const float* Wb1   = (const float*)d_in[8];
  const float* pw    = (const float*)d_in[9];
  const float* Wd1   = (const float*)d_in[10];
  const float* bd1   = (const float*)d_in[11];
  const float* Wd2   = (const float*)d_in[12];
  const float* bd2   = (const float*)d_in[13];
  const float* Wb0l  = (const float*)d_in[14];
  const float* Wb1l  = (const float*)d_in[15];
  const float* pwl   = (const float*)d_in[16];
  const float* Wd1l  = (const float*)d_in[17];
  const float* bd1l  = (const float*)d_in[18];
  const float* Wd2l  = (const float*)d_in[19];
  const float* bd2l  = (const float*)d_in[20];
  const float* w_out = (const float*)d_in[21];
  const float* ebias = (const float*)d_in[22];

  float* out = (float*)d_out;
  float* energy = out;          // (B,)
  float* forces = out + B_;     // (N,3)

  float* ws = nullptr;
  (void)hipGetSymbolAddress((void**)&ws, HIP_SYMBOL(g_ws));

  const size_t NF = (size_t)N_ * F_;
  const size_t NV = (size_t)N_ * 3 * F_;
  float* rd       = ws;                       // E*32 (rad | drad)
  float* u3       = rd + (size_t)E_*32;       // E*3
  float* rr       = u3 + (size_t)E_*3;        // E
  float* s        = rr + E_;                  // N*F
  float* v        = s + NF;                   // N*3F
  float* ps       = v + NV;                   // N*F
  float* pv       = ps + NF;                  // N*3F
  float* ys       = pv + NV;                  // N*F
  float* yv       = ys + NF;                  // N*3F
  float* yps      = yv + NV;                  // N*F
  float* ypv      = yps + NF;                 // N*3F
  float* Gs       = ypv + NV;                 // N*F
  float* Gv       = Gs + NF;                  // N*3F
  float* Gps      = Gv + NV;                  // N*F
  float* Gpv      = Gps + NF;                 // N*3F
  float* grad_r   = Gpv + NV;                 // E
  float* grad_u   = grad_r + E_;              // E*3
  float* a_s      = grad_u + (size_t)E_*3;    // 4*N*F
  float* a_v      = a_s + 4*NF;               // 4*N*3F
  float* a_ps     = a_v + 4*NV;               // 4*N*F
  float* a_pv     = a_ps + 4*NF;              // 4*N*3F
  float* a_l      = a_pv + 4*NV;              // N*F
  // int region (CSR + sort)
  int* iws        = (int*)(a_l + NF);
  int* cntd       = iws;                      // N
  int* cnts       = cntd + N_;                // N
  int* dst_off    = cnts + N_;                // N+1
  int* src_off    = dst_off + (N_+1);         // N+1
  int* dst_perm   = src_off + (N_+1);         // E
  int* src_perm   = dst_perm + E_;            // E
  int* curd       = src_perm + E_;            // N
  int* curs       = curd + N_;                // N
  int* binc       = curs + N_;                // 128
  int* bcur       = binc + 128;               // 128
  int* ord_d      = bcur + 128;               // N
  int* ord_s      = ord_d + N_;               // N

  const int TB = 256;
  const int nodeBlocks = (int)(NF / TB);             // 6250 (also = N*32/256 for CSR kernels)
  const int eThreadBlocks = (E_ + TB - 1) / TB;      // 1563
  const int nThreadBlocks = (N_ + TB - 1) / TB;      // 196

  // ---- CSR build + degree sort ----
  fill_int_kernel<<<256, TB, 0, stream>>>(cntd, (size_t)2*N_, 0);
  fill_int_kernel<<<1, 128, 0, stream>>>(binc, 128, 0);
  hist_kernel<<<eThreadBlocks, TB, 0, stream>>>(dst, src, cntd, cnts);
  scan_kernel<<<2, 1024, 0, stream>>>(cntd, cnts, dst_off, src_off);
  cursor_init_kernel<<<nThreadBlocks, TB, 0, stream>>>(dst_off, src_off, curd, curs);
  scatter_kernel<<<eThreadBlocks, TB, 0, stream>>>(dst, src, curd, curs, dst_perm, src_perm);
  sort_hist_kernel<<<nThreadBlocks, TB, 0, stream>>>(dst_off, src_off, binc);
  sort_scan_kernel<<<1, 64, 0, stream>>>(binc, bcur);
  sort_scatter_kernel<<<nThreadBlocks, TB, 0, stream>>>(dst_off, src_off, bcur, ord_d, ord_s);

  // ---- init state + geometry ----
  fill_kernel<<<2048, TB, 0, stream>>>(v, 7*NF, 0.f);  // v,ps,pv = 0
  init_embed_kernel<<<nodeBlocks, TB, 0, stream>>>(s, embed, Z);
  geom_kernel<<<eThreadBlocks, TB, 0, stream>>>(pos, dst, src, rd, u3, rr);

  // ---- 4 full equivariant passes ----
  for (int i = 0; i < 4; ++i) {
    edge_fwd_csr<<<nodeBlocks, TB, 0, stream>>>(
        ord_d, dst_off, dst_perm, src, rd, u3,
        Wb0 + (size_t)i*K_*F_, Wb1 + (size_t)i*K_*F_, pw + (size_t)i*10*F_,
        s, v, ps, pv, ys, yv, yps, ypv);
    node_fwd_kernel<<<nodeBlocks, TB, 0, stream>>>(
        s, v, ps, pv, ys, yv, yps, ypv,
        Wd1 + (size_t)i*4*F_*F_, bd1 + (size_t)i*F_,
        Wd2 + (size_t)i*4*F_*F_, bd2 + (size_t)i*F_,
        a_s + i*NF, a_v + i*NV, a_ps + i*NF, a_pv + i*NV);
  }

  // ---- last scalar pass ----
  fill_kernel<<<592, TB, 0, stream>>>(out, (size_t)(B_ + N_*3), 0.f);
  edge_fwd_last_csr<<<nodeBlocks, TB, 0, stream>>>(
      ord_d, dst_off, dst_perm, src, rd, u3, Wb0l, Wb1l, pwl, s, v, ys);
  node_fwd_last_kernel<<<nodeBlocks, TB, 0, stream>>>(
      s, ys, Wd1l, bd1l, Wd2l, bd2l, a_l, w_out, ebias, Z, bseg, energy);

  // ---- backward init ----
  init_gs_kernel<<<nodeBlocks, TB, 0, stream>>>(Gs, w_out);
  fill_kernel<<<2048, TB, 0, stream>>>(Gv, 7*NF, 0.f);

  // ---- last pass backward (writes grad_r/grad_u, no fill needed) ----
  b1_last_kernel<<<nodeBlocks, TB, 0, stream>>>(s, a_l, Wd1l, Wd2l, bd2l, Gs, ys);
  b2m_last_kernel<<<nodeBlocks, TB, 0, stream>>>(
      ord_s, src_off, src_perm, dst, rd, u3, Wb0l, Wb1l, pwl, s, v, ys,
      Gs, Gv, grad_r, grad_u);

  // ---- 4 full passes backward ----
  for (int i = 3; i >= 0; --i) {
    b1_kernel<<<nodeBlocks, TB, 0, stream>>>(
        s, v, ps, pv,
        a_s + i*NF, a_v + i*NV, a_ps + i*NF, a_pv + i*NV,
        Wd1 + (size_t)i*4*F_*F_, Wd2 + (size_t)i*4*F_*F_, bd2 + (size_t)i*F_,
        Gs, Gv, Gps, Gpv, ys, yv, yps, ypv);
    b2m_kernel<<<nodeBlocks, TB, 0, stream>>>(
        ord_s, src_off, src_perm, dst, rd, u3,
        Wb0 + (size_t)i*K_*F_, Wb1 + (size_t)i*K_*F_, pw + (size_t)i*10*F_,
        s, v, ps, pv, ys, yv, yps, ypv, Gs, Gv, Gps, Gpv, grad_r, grad_u);
  }

  // ---- basis backward -> forces ----
  basis_bwd_kernel<<<eThreadBlocks, TB, 0, stream>>>(
      dst, src, rr, u3, grad_r, grad_u, forces);
}